// Round 1
// baseline (183875.256 us; speedup 1.0000x reference)
//
#include <hip/hip_runtime.h>
#include <hip/hip_cooperative_groups.h>

namespace cg = cooperative_groups;

#define T_   512
#define B_   128
#define E_   512
#define H_   512
#define G4_  2048
#define MEM_ 500
#define CTX_ 300
#define EC_  (E_ + CTX_)
#define NAWG_ 100   // WGs per dir owning attention columns (5 each -> 500)

struct ScanParams {
  const float* __restrict__ x;     // [B,T,E]
  const int*   __restrict__ len;   // [B]
  const float* __restrict__ Wih0; const float* __restrict__ Whh0;
  const float* __restrict__ bih0; const float* __restrict__ bhh0;
  const float* __restrict__ Wih1; const float* __restrict__ Whh1;
  const float* __restrict__ bih1; const float* __restrict__ bhh1;
  const float* __restrict__ Mk0;  const float* __restrict__ Mk1;
  const float* __restrict__ Mf;   // [2,MEM,4H]  (ws, precomputed)
  float* __restrict__ h;          // [2,B,H]
  float* __restrict__ c;          // [2,B,H]
  float* __restrict__ hm;         // [2,B,H]  (bwd masked hidden)
  float* __restrict__ G;          // [2,4H,B]  transposed gate partials
  float* __restrict__ aT;         // [2,MEM,B] transposed exp-logits
  float* __restrict__ Sp;         // [2,NAWG,B] softmax partial row-sums
  float* __restrict__ out;        // [B,2H]
};

__device__ __forceinline__ float sigm_(float x) { return 1.f / (1.f + __expf(-x)); }
__device__ __forceinline__ float tanh_(float x) { return 1.f - 2.f / (__expf(2.f * x) + 1.f); }

// Mfused[d][m][j] = sum_c Mv_d[c][m] * Wih_d[j][E+c]
__global__ __launch_bounds__(256) void mfused_kernel(
    const float* __restrict__ WihF, const float* __restrict__ WihB,
    const float* __restrict__ MvF,  const float* __restrict__ MvB,
    float* __restrict__ Mf) {
  const int d  = blockIdx.x >> 7;
  const int j0 = (blockIdx.x & 127) * 16;
  const float* __restrict__ Wih = d ? WihB : WihF;
  const float* __restrict__ Mv  = d ? MvB  : MvF;
  __shared__ float Wl[16][CTX_ + 1];
  for (int i = threadIdx.x; i < 16 * CTX_; i += 256) {
    int r = i / CTX_, cc = i - r * CTX_;
    Wl[r][cc] = Wih[(size_t)(j0 + r) * EC_ + E_ + cc];
  }
  __syncthreads();
  const int jj = threadIdx.x & 15;
  for (int m = threadIdx.x >> 4; m < MEM_; m += 16) {
    float acc = 0.f;
    for (int cc = 0; cc < CTX_; ++cc)
      acc = fmaf(Mv[cc * MEM_ + m], Wl[jj][cc], acc);
    Mf[(size_t)d * MEM_ * G4_ + (size_t)m * G4_ + j0 + jj] = acc;
  }
}

__global__ __launch_bounds__(256) void scan_kernel(ScanParams p) {
  cg::grid_group grid = cg::this_grid();
  const int dir  = blockIdx.x >> 7;   // 0 fwd, 1 bwd
  const int wg   = blockIdx.x & 127;
  const int tid  = threadIdx.x;
  const int b    = tid & 127;
  const int half = tid >> 7;

  __shared__ float A[128][129];       // staged activation chunk (pad: 129%32==1 -> 2-way, free)
  __shared__ float sred[128][2];

  const float* __restrict__ Wih = dir ? p.Wih1 : p.Wih0;
  const float* __restrict__ Whh = dir ? p.Whh1 : p.Whh0;
  const float* __restrict__ bih = dir ? p.bih1 : p.bih0;
  const float* __restrict__ bhh = dir ? p.bhh1 : p.bhh0;
  const float* __restrict__ Mk  = dir ? p.Mk1  : p.Mk0;
  const float* __restrict__ Mf  = p.Mf + (size_t)dir * MEM_ * G4_;
  float* __restrict__ h  = p.h  + dir * B_ * H_;
  float* __restrict__ c  = p.c  + dir * B_ * H_;
  float* __restrict__ hm = p.hm + dir * B_ * H_;
  float* __restrict__ G  = p.G  + dir * G4_ * B_;
  float* __restrict__ aT = p.aT + dir * MEM_ * B_;
  float* __restrict__ Sp = p.Sp + dir * NAWG_ * B_;

  const int myLen = p.len[b];
  const int nA    = (wg < NAWG_) ? (half ? 2 : 3) : 0;
  const int mBase = wg * 5 + (half ? 3 : 0);
  const int jbase = wg * 16 + half * 8;   // 16 gate cols per WG, 8 per half
  const int u0    = wg * 4 + half * 2;    // 4 hidden units per WG, 2 per half

  for (int s = 0; s < T_; ++s) {
    const int t = dir ? (T_ - 1 - s) : s;

    // ---------------- phase 1a: gate partials  G = [x_t | h] @ [Wih_x|Whh]^T
    float acc[8] = {0.f,0.f,0.f,0.f,0.f,0.f,0.f,0.f};
    for (int ch = 0; ch < 8; ++ch) {
      const int k0 = ch * 128;
      __syncthreads();                    // protect A from previous chunk's readers
      if (k0 < E_) {
        const float* __restrict__ src = p.x + (size_t)t * E_ + k0;
        for (int i = tid; i < 128 * 128; i += 256) {
          int bb = i >> 7, kk = i & 127;
          A[bb][kk] = src[(size_t)bb * (T_ * E_) + kk];
        }
      } else {
        const float* __restrict__ src = h + (k0 - E_);
        for (int i = tid; i < 128 * 128; i += 256) {
          int bb = i >> 7, kk = i & 127;
          A[bb][kk] = src[bb * H_ + kk];
        }
      }
      __syncthreads();
      const float* __restrict__ w0 =
          (k0 < E_) ? (Wih + (size_t)jbase * EC_ + k0)
                    : (Whh + (size_t)jbase * H_ + (k0 - E_));
      const int wstr = (k0 < E_) ? EC_ : H_;
      for (int kk = 0; kk < 128; ++kk) {
        const float av = A[b][kk];
        #pragma unroll
        for (int jj = 0; jj < 8; ++jj)
          acc[jj] = fmaf(av, w0[jj * wstr + kk], acc[jj]);
      }
    }
    #pragma unroll
    for (int jj = 0; jj < 8; ++jj)
      G[(jbase + jj) * B_ + b] = acc[jj];   // transposed -> coalesced both sides

    // ---------------- phase 1b: a = exp(h_mem @ Mk^T), partial row-sums
    if (wg < NAWG_) {
      float aacc[3] = {0.f, 0.f, 0.f};
      const float* __restrict__ hmem = dir ? hm : h;   // bwd uses masked hidden
      for (int ch = 0; ch < 4; ++ch) {
        const int k0 = ch * 128;
        __syncthreads();
        for (int i = tid; i < 128 * 128; i += 256) {
          int bb = i >> 7, kk = i & 127;
          A[bb][kk] = hmem[bb * H_ + k0 + kk];
        }
        __syncthreads();
        for (int kk = 0; kk < 128; ++kk) {
          const float av = A[b][kk];
          #pragma unroll
          for (int q = 0; q < 3; ++q)
            if (q < nA)
              aacc[q] = fmaf(av, Mk[(mBase + q) * H_ + k0 + kk], aacc[q]);
        }
      }
      float spart = 0.f;
      #pragma unroll
      for (int q = 0; q < 3; ++q)
        if (q < nA) {
          float e = __expf(aacc[q]);
          aT[(mBase + q) * B_ + b] = e;
          spart += e;
        }
      sred[b][half] = spart;
      __syncthreads();
      if (half == 0) Sp[wg * B_ + b] = sred[b][0] + sred[b][1];
    }

    grid.sync();

    // ---------------- phase 2: ctx matmul + cell update
    float g8[8];
    #pragma unroll
    for (int i2 = 0; i2 < 8; ++i2) {
      const int q = i2 >> 1, uu = i2 & 1;
      const int col = q * H_ + u0 + uu;
      g8[i2] = G[col * B_ + b] + bih[col] + bhh[col];
    }
    if (s > 0) {   // flag: step 0 uses zero context
      float sb = 0.f;
      for (int w = 0; w < NAWG_; ++w) sb += Sp[w * B_ + b];
      float ctx[8] = {0.f,0.f,0.f,0.f,0.f,0.f,0.f,0.f};
      for (int m = 0; m < MEM_; ++m) {
        const float av = aT[m * B_ + b];
        #pragma unroll
        for (int i2 = 0; i2 < 8; ++i2) {
          const int q = i2 >> 1, uu = i2 & 1;
          ctx[i2] = fmaf(av, Mf[(size_t)m * G4_ + q * H_ + u0 + uu], ctx[i2]);
        }
      }
      const float inv = 1.f / sb;
      #pragma unroll
      for (int i2 = 0; i2 < 8; ++i2) g8[i2] += ctx[i2] * inv;
    }
    #pragma unroll
    for (int uu = 0; uu < 2; ++uu) {
      const int u = u0 + uu;
      const float gi = g8[0 + uu], gf = g8[2 + uu], gg = g8[4 + uu], go = g8[6 + uu];
      float cv = c[b * H_ + u];
      cv = sigm_(gf) * cv + sigm_(gi) * tanh_(gg);
      const float hv = sigm_(go) * tanh_(cv);
      c[b * H_ + u] = cv;
      h[b * H_ + u] = hv;
      if (dir == 0) {
        if (t == myLen - 1) p.out[b * (2 * H_) + 2 * u] = hv;  // final valid fwd hidden
      } else {
        hm[b * H_ + u] = (t < myLen) ? hv : 0.f;               // masked hidden -> next mem read
        if (s == T_ - 1) p.out[b * (2 * H_) + 2 * u + 1] = hv; // mask(t=0)==1 always (len>=1)
      }
    }
    grid.sync();
  }
}

extern "C" void kernel_launch(void* const* d_in, const int* in_sizes, int n_in,
                              void* d_out, int out_size, void* d_ws, size_t ws_size,
                              hipStream_t stream) {
  (void)in_sizes; (void)n_in; (void)out_size; (void)ws_size;

  ScanParams p;
  p.x    = (const float*)d_in[0];
  p.len  = (const int*)  d_in[1];
  p.Wih0 = (const float*)d_in[2];
  p.Whh0 = (const float*)d_in[3];
  p.bih0 = (const float*)d_in[4];
  p.bhh0 = (const float*)d_in[5];
  p.Wih1 = (const float*)d_in[6];
  p.Whh1 = (const float*)d_in[7];
  p.bih1 = (const float*)d_in[8];
  p.bhh1 = (const float*)d_in[9];
  p.Mk0  = (const float*)d_in[10];
  const float* MvF = (const float*)d_in[11];
  p.Mk1  = (const float*)d_in[12];
  const float* MvB = (const float*)d_in[13];

  float* ws = (float*)d_ws;
  size_t o = 0;
  float* Mf = ws + o; o += (size_t)2 * MEM_ * G4_;   // 2,048,000 f
  float* h  = ws + o; o += (size_t)2 * B_ * H_;      // h, c, hm contiguous (one memset)
  float* c  = ws + o; o += (size_t)2 * B_ * H_;
  float* hm = ws + o; o += (size_t)2 * B_ * H_;
  float* G  = ws + o; o += (size_t)2 * G4_ * B_;
  float* aT = ws + o; o += (size_t)2 * MEM_ * B_;
  float* Sp = ws + o; o += (size_t)2 * NAWG_ * B_;
  p.Mf = Mf; p.h = h; p.c = c; p.hm = hm; p.G = G; p.aT = aT; p.Sp = Sp;
  p.out = (float*)d_out;

  // zero recurrent state each call (deterministic; h,c,hm are contiguous)
  hipMemsetAsync(h, 0, (size_t)3 * 2 * B_ * H_ * sizeof(float), stream);

  mfused_kernel<<<dim3(256), dim3(256), 0, stream>>>(
      (const float*)d_in[2], (const float*)d_in[6], MvF, MvB, Mf);

  void* args[] = { &p };
  hipLaunchCooperativeKernel((const void*)scan_kernel, dim3(256), dim3(256),
                             args, 0, stream);
}

// Round 2
// 45400.928 us; speedup vs baseline: 4.0500x; 4.0500x over previous
//
#include <hip/hip_runtime.h>
#include <hip/hip_bf16.h>
#include <hip/hip_cooperative_groups.h>

namespace cg = cooperative_groups;

#define T_   512
#define B_   128
#define E_   512
#define H_   512
#define G4_  2048
#define MEM_ 500
#define CTX_ 300
#define EC_  (E_ + CTX_)

typedef short sh8  __attribute__((ext_vector_type(8)));   // 8 bf16 (4 VGPR) MFMA frag
typedef float f32x4 __attribute__((ext_vector_type(4)));

struct ScanParams {
  const float* __restrict__ x;     // [B,T,E]
  const int*   __restrict__ len;   // [B]
  const float* __restrict__ Wih0; const float* __restrict__ Whh0;
  const float* __restrict__ bih0; const float* __restrict__ bhh0;
  const float* __restrict__ Wih1; const float* __restrict__ Whh1;
  const float* __restrict__ bih1; const float* __restrict__ bhh1;
  const float* __restrict__ Mk0;  const float* __restrict__ Mk1;
  const float* __restrict__ Mf;   // [2,MEM,4H] fp32 (ws, precomputed)
  short* __restrict__ hbf;        // [2,B,H]  bf16 hidden
  short* __restrict__ hmbf;       // [B,H]    bf16 masked bwd hidden
  short* __restrict__ aB;         // [2,B,512] bf16 exp-logits (cols >=500 always 0)
  float* __restrict__ G;          // [2,4H,B] fp32 gate partials (transposed)
  float* __restrict__ Sp;         // [2,B,32] fp32 softmax partial sums per coltile
  float* __restrict__ out;        // [B,2H] fp32
};

__device__ __forceinline__ float sigm_(float x) { return 1.f / (1.f + __expf(-x)); }
__device__ __forceinline__ float tanh_(float x) { return 1.f - 2.f / (__expf(2.f * x) + 1.f); }
__device__ __forceinline__ short f2bs(float f) {
  __hip_bfloat16 h = __float2bfloat16(f);
  short s; __builtin_memcpy(&s, &h, 2); return s;
}

// Mfused[d][m][j] = sum_c Mv_d[c][m] * Wih_d[j][E+c]   (fp32, as round 0)
__global__ __launch_bounds__(256) void mfused_kernel(
    const float* __restrict__ WihF, const float* __restrict__ WihB,
    const float* __restrict__ MvF,  const float* __restrict__ MvB,
    float* __restrict__ Mf) {
  const int d  = blockIdx.x >> 7;
  const int j0 = (blockIdx.x & 127) * 16;
  const float* __restrict__ Wih = d ? WihB : WihF;
  const float* __restrict__ Mv  = d ? MvB  : MvF;
  __shared__ float Wl[16][CTX_ + 1];
  for (int i = threadIdx.x; i < 16 * CTX_; i += 256) {
    int r = i / CTX_, cc = i - r * CTX_;
    Wl[r][cc] = Wih[(size_t)(j0 + r) * EC_ + E_ + cc];
  }
  __syncthreads();
  const int jj = threadIdx.x & 15;
  for (int m = threadIdx.x >> 4; m < MEM_; m += 16) {
    float acc = 0.f;
    for (int cc = 0; cc < CTX_; ++cc)
      acc = fmaf(Mv[cc * MEM_ + m], Wl[jj][cc], acc);
    Mf[(size_t)d * MEM_ * G4_ + (size_t)m * G4_ + j0 + jj] = acc;
  }
}

__global__ __launch_bounds__(256, 1) void scan_kernel(ScanParams p) {
  cg::grid_group grid = cg::this_grid();
  const int dir  = blockIdx.x >> 7;   // 0 fwd, 1 bwd
  const int w    = blockIdx.x & 127;  // WG within dir: gate coltile w, units 4w..4w+3
  const int tid  = threadIdx.x;
  const int wv   = tid >> 6;          // wave 0..3
  const int lane = tid & 63;

  // LDS: all weights in MFMA B-fragment order -> linear per-lane ds_read_b128, no conflicts
  __shared__ __align__(16) short WgL[32 * 64 * 8];  // gates W  [16 cols][K=1024]  32 KB
  __shared__ __align__(16) short MkL[16 * 64 * 8];  // attn Mk  [16 cols][K=512]   16 KB
  __shared__ __align__(16) short MfL[16 * 64 * 8];  // ctx  Mf  [16 cellcols][512] 16 KB
  __shared__ float SvL[B_];                         // 1/softmax-denominator per b
  __shared__ int   LvL[B_];

  const float* __restrict__ Wihd = dir ? p.Wih1 : p.Wih0;
  const float* __restrict__ Whhd = dir ? p.Whh1 : p.Whh0;
  const float* __restrict__ bihd = dir ? p.bih1 : p.bih0;
  const float* __restrict__ bhhd = dir ? p.bhh1 : p.bhh0;
  const float* __restrict__ Mkd  = dir ? p.Mk1  : p.Mk0;
  const float* __restrict__ Mfd  = p.Mf + (size_t)dir * MEM_ * G4_;
  short* __restrict__ hbd  = p.hbf + (size_t)dir * B_ * H_;
  short* __restrict__ aBd  = p.aB  + (size_t)dir * B_ * 512;
  float* __restrict__ Gd   = p.G   + (size_t)dir * G4_ * B_;
  float* __restrict__ Spd  = p.Sp  + (size_t)dir * B_ * 32;

  // attn ownership: units 2w,2w+1 -> waves 0,1; both share coltile ct
  const int ct = w >> 2;

  // ---- one-time LDS preload (fragment order: [kstep][lane][8]) ----
  for (int i = tid; i < 2048; i += 256) {           // gates: 32 ksteps
    const int ks = i >> 6, l2 = i & 63;
    const int col = l2 & 15, kg = l2 >> 4;
    const int k0 = ks * 32 + kg * 8;
    const int gc = 16 * w + col;
    const float* src = (k0 < E_) ? (Wihd + (size_t)gc * EC_ + k0)
                                 : (Whhd + (size_t)gc * H_ + (k0 - E_));
    sh8 v;
    #pragma unroll
    for (int j = 0; j < 8; ++j) v[j] = f2bs(src[j]);
    *reinterpret_cast<sh8*>(&WgL[i * 8]) = v;
  }
  for (int i = tid; i < 1024; i += 256) {           // Mk: 16 ksteps
    const int ks = i >> 6, l2 = i & 63;
    const int col = l2 & 15, kg = l2 >> 4;
    const int k0 = ks * 32 + kg * 8;
    const int mr = 16 * ct + col;
    sh8 v;
    #pragma unroll
    for (int j = 0; j < 8; ++j)
      v[j] = (mr < MEM_) ? f2bs(Mkd[(size_t)mr * H_ + k0 + j]) : (short)0;
    *reinterpret_cast<sh8*>(&MkL[i * 8]) = v;
  }
  for (int i = tid; i < 1024; i += 256) {           // Mf cell slice: 16 ksteps
    const int ks = i >> 6, l2 = i & 63;
    const int col = l2 & 15, kg = l2 >> 4;
    const int q2 = col & 3, u2 = col >> 2;
    const int gc = q2 * H_ + 4 * w + u2;
    const int k0 = ks * 32 + kg * 8;
    sh8 v;
    #pragma unroll
    for (int j = 0; j < 8; ++j) {
      const int m = k0 + j;
      v[j] = (m < MEM_) ? f2bs(Mfd[(size_t)m * G4_ + gc]) : (short)0;
    }
    *reinterpret_cast<sh8*>(&MfL[i * 8]) = v;
  }
  if (tid < B_) LvL[tid] = p.len[tid];

  // per-lane cell column mapping: c -> (quadrant q, unit offset uu)
  const int c  = lane & 15;
  const int q  = c & 3;
  const int uu = c >> 2;
  const int gcol = q * H_ + 4 * w + uu;
  const float biasl = bihd[gcol] + bhhd[gcol];

  float creg[2][4] = {{0.f,0.f,0.f,0.f},{0.f,0.f,0.f,0.f}};  // cell state, registers only
  __syncthreads();

  for (int s = 0; s < T_; ++s) {
    const int t = dir ? (T_ - 1 - s) : s;

    // ================= phase 1a: gate partials via MFMA (K=1024) =================
    f32x4 accG[2] = {(f32x4){0,0,0,0}, (f32x4){0,0,0,0}};
    {
      const int kg8 = (lane >> 4) * 8;
      for (int ks = 0; ks < 16; ++ks) {             // x half (fp32 -> bf16 on the fly)
        const int k0 = ks * 32 + kg8;
        sh8 bfrag = *reinterpret_cast<const sh8*>(&WgL[(ks * 64 + lane) * 8]);
        #pragma unroll
        for (int tt = 0; tt < 2; ++tt) {
          const int brow = 32 * wv + 16 * tt + (lane & 15);
          const float* xp = p.x + ((size_t)brow * T_ + t) * E_ + k0;
          f32x4 v0 = *reinterpret_cast<const f32x4*>(xp);
          f32x4 v1 = *reinterpret_cast<const f32x4*>(xp + 4);
          sh8 afrag;
          #pragma unroll
          for (int j = 0; j < 4; ++j) { afrag[j] = f2bs(v0[j]); afrag[4+j] = f2bs(v1[j]); }
          accG[tt] = __builtin_amdgcn_mfma_f32_16x16x32_bf16(afrag, bfrag, accG[tt], 0, 0, 0);
        }
      }
      for (int ks = 16; ks < 32; ++ks) {            // h half (bf16 direct)
        const int kh = (ks - 16) * 32 + kg8;
        sh8 bfrag = *reinterpret_cast<const sh8*>(&WgL[(ks * 64 + lane) * 8]);
        #pragma unroll
        for (int tt = 0; tt < 2; ++tt) {
          const int brow = 32 * wv + 16 * tt + (lane & 15);
          sh8 afrag = *reinterpret_cast<const sh8*>(hbd + brow * H_ + kh);
          accG[tt] = __builtin_amdgcn_mfma_f32_16x16x32_bf16(afrag, bfrag, accG[tt], 0, 0, 0);
        }
      }
      #pragma unroll
      for (int tt = 0; tt < 2; ++tt) {              // C layout: col=lane&15, row=4*(lane>>4)+reg
        const int gc = 16 * w + (lane & 15);
        const int b0 = 32 * wv + 16 * tt + 4 * (lane >> 4);
        *reinterpret_cast<f32x4*>(Gd + gc * B_ + b0) = accG[tt];
      }
    }

    // ================= phase 1b: attn logits -> exp -> aB, partial sums ==========
    if (wv < 2) {
      const int uid = 2 * w + wv;
      const int mt  = uid & 7;
      const short* __restrict__ hmem = dir ? p.hmbf : p.hbf;  // bwd reads masked hidden
      const int brow = 16 * mt + (lane & 15);
      const int kg8  = (lane >> 4) * 8;
      f32x4 accA = (f32x4){0,0,0,0};
      for (int ks = 0; ks < 16; ++ks) {
        sh8 afrag = *reinterpret_cast<const sh8*>(hmem + brow * H_ + ks * 32 + kg8);
        sh8 bfrag = *reinterpret_cast<const sh8*>(&MkL[(ks * 64 + lane) * 8]);
        accA = __builtin_amdgcn_mfma_f32_16x16x32_bf16(afrag, bfrag, accA, 0, 0, 0);
      }
      const int m = 16 * ct + (lane & 15);
      float e[4];
      #pragma unroll
      for (int r = 0; r < 4; ++r) e[r] = (m < MEM_) ? __expf(accA[r]) : 0.f;
      #pragma unroll
      for (int r = 0; r < 4; ++r) {
        const int b = 16 * mt + 4 * (lane >> 4) + r;
        aBd[b * 512 + m] = f2bs(e[r]);
      }
      #pragma unroll
      for (int r = 0; r < 4; ++r) {                 // butterfly over the 16 m-lanes
        e[r] += __shfl_xor(e[r], 1);
        e[r] += __shfl_xor(e[r], 2);
        e[r] += __shfl_xor(e[r], 4);
        e[r] += __shfl_xor(e[r], 8);
      }
      if ((lane & 15) == 0) {
        #pragma unroll
        for (int r = 0; r < 4; ++r)
          Spd[(16 * mt + 4 * (lane >> 4) + r) * 32 + ct] = e[r];
      }
    }

    grid.sync();

    // ====== softmax denominator (deterministic): 1/sum over 32 coltiles ======
    if (tid < B_) {
      const float* sp = Spd + tid * 32;
      float sm = 0.f;
      #pragma unroll
      for (int i4 = 0; i4 < 8; ++i4) {
        f32x4 v = *reinterpret_cast<const f32x4*>(sp + 4 * i4);
        sm += v[0] + v[1] + v[2] + v[3];
      }
      SvL[tid] = 1.f / sm;
    }

    // ================= phase 2: ctx MFMA for own cell cols (K=512 pad) ==========
    f32x4 accC[2] = {(f32x4){0,0,0,0}, (f32x4){0,0,0,0}};
    if (s > 0) {
      const int kg8 = (lane >> 4) * 8;
      for (int ks = 0; ks < 16; ++ks) {
        sh8 bfrag = *reinterpret_cast<const sh8*>(&MfL[(ks * 64 + lane) * 8]);
        #pragma unroll
        for (int tt = 0; tt < 2; ++tt) {
          const int brow = 32 * wv + 16 * tt + (lane & 15);
          sh8 afrag = *reinterpret_cast<const sh8*>(aBd + brow * 512 + ks * 32 + kg8);
          accC[tt] = __builtin_amdgcn_mfma_f32_16x16x32_bf16(afrag, bfrag, accC[tt], 0, 0, 0);
        }
      }
    }
    __syncthreads();                                // SvL ready for all waves

    // ================= cell update (registers, redundant x4 across q-lanes) =====
    #pragma unroll
    for (int tt = 0; tt < 2; ++tt) {
      const int b0 = 32 * wv + 16 * tt + 4 * (lane >> 4);
      f32x4 gp = *reinterpret_cast<const f32x4*>(Gd + gcol * B_ + b0);
      float g4[4];
      #pragma unroll
      for (int r = 0; r < 4; ++r) {
        float v = gp[r] + biasl;
        if (s > 0) v += accC[tt][r] * SvL[b0 + r];
        g4[r] = v;
      }
      #pragma unroll
      for (int r = 0; r < 4; ++r) {
        const float x1 = __shfl_xor(g4[r], 1);
        const float x2 = __shfl_xor(g4[r], 2);
        const float x3 = __shfl_xor(g4[r], 3);
        const float iv = (q==0)?g4[r]:(q==1)?x1:(q==2)?x2:x3;
        const float fv = (q==0)?x1:(q==1)?g4[r]:(q==2)?x3:x2;
        const float gv = (q==0)?x2:(q==1)?x3:(q==2)?g4[r]:x1;
        const float ov = (q==0)?x3:(q==1)?x2:(q==2)?x1:g4[r];
        float cv = creg[tt][r];
        cv = sigm_(fv) * cv + sigm_(iv) * tanh_(gv);
        const float hv = sigm_(ov) * tanh_(cv);
        creg[tt][r] = cv;
        if (q == 0) {
          const int b    = b0 + r;
          const int unit = 4 * w + uu;
          if (dir == 0) {
            hbd[b * H_ + unit] = f2bs(hv);
            if (t == LvL[b] - 1) p.out[b * (2 * H_) + 2 * unit] = hv;
          } else {
            const short hs = f2bs(hv);
            hbd[b * H_ + unit]    = hs;
            p.hmbf[b * H_ + unit] = (t < LvL[b]) ? hs : (short)0;
            if (s == T_ - 1) p.out[b * (2 * H_) + 2 * unit + 1] = hv;
          }
        }
      }
    }

    grid.sync();
  }
}

extern "C" void kernel_launch(void* const* d_in, const int* in_sizes, int n_in,
                              void* d_out, int out_size, void* d_ws, size_t ws_size,
                              hipStream_t stream) {
  (void)in_sizes; (void)n_in; (void)out_size; (void)ws_size;

  ScanParams p;
  p.x    = (const float*)d_in[0];
  p.len  = (const int*)  d_in[1];
  p.Wih0 = (const float*)d_in[2];
  p.Whh0 = (const float*)d_in[3];
  p.bih0 = (const float*)d_in[4];
  p.bhh0 = (const float*)d_in[5];
  p.Wih1 = (const float*)d_in[6];
  p.Whh1 = (const float*)d_in[7];
  p.bih1 = (const float*)d_in[8];
  p.bhh1 = (const float*)d_in[9];
  p.Mk0  = (const float*)d_in[10];
  const float* MvF = (const float*)d_in[11];
  p.Mk1  = (const float*)d_in[12];
  const float* MvB = (const float*)d_in[13];

  char* ws = (char*)d_ws;
  size_t off = 0;
  auto alloc = [&](size_t bytes) -> void* {
    void* ptr = ws + off; off += (bytes + 255) & ~(size_t)255; return ptr;
  };
  float* Mf   = (float*)alloc((size_t)2 * MEM_ * G4_ * 4);   // 8.19 MB
  short* hbf  = (short*)alloc((size_t)2 * B_ * H_ * 2);      // 256 KB
  short* hmbf = (short*)alloc((size_t)B_ * H_ * 2);          // 128 KB
  short* aB   = (short*)alloc((size_t)2 * B_ * 512 * 2);     // 256 KB
  float* G    = (float*)alloc((size_t)2 * G4_ * B_ * 4);     // 2 MB
  float* Sp   = (float*)alloc((size_t)2 * B_ * 32 * 4);      // 32 KB
  p.Mf = Mf; p.hbf = hbf; p.hmbf = hmbf; p.aB = aB; p.G = G; p.Sp = Sp;
  p.out = (float*)d_out;

  // zero bf16 recurrent state (hbf + hmbf are contiguous, sizes 256-aligned)
  hipMemsetAsync(hbf, 0, (size_t)3 * B_ * H_ * 2, stream);

  mfused_kernel<<<dim3(256), dim3(256), 0, stream>>>(
      (const float*)d_in[2], (const float*)d_in[6], MvF, MvB, Mf);

  void* args[] = { &p };
  hipLaunchCooperativeKernel((const void*)scan_kernel, dim3(256), dim3(256),
                             args, 0, stream);
}

// Round 3
// 23825.130 us; speedup vs baseline: 7.7177x; 1.9056x over previous
//
#include <hip/hip_runtime.h>
#include <hip/hip_bf16.h>

#define T_   512
#define B_   128
#define E_   512
#define H_   512
#define G4_  2048
#define MEM_ 500
#define CTX_ 300
#define EC_  (E_ + CTX_)

typedef short sh8  __attribute__((ext_vector_type(8)));   // 8 bf16 (4 VGPR) MFMA frag
typedef float f32x4 __attribute__((ext_vector_type(4)));

struct ScanParams {
  const float* __restrict__ x;     // [B,T,E] fp32
  const short* __restrict__ xbf;   // [B,T,E] bf16 (ws precomputed; may be null)
  const int*   __restrict__ len;   // [B]
  const float* __restrict__ Wih0; const float* __restrict__ Whh0;
  const float* __restrict__ bih0; const float* __restrict__ bhh0;
  const float* __restrict__ Wih1; const float* __restrict__ Whh1;
  const float* __restrict__ bih1; const float* __restrict__ bhh1;
  const float* __restrict__ Mk0;  const float* __restrict__ Mk1;
  const float* __restrict__ Mf;   // [2,MEM,4H] fp32 (ws, precomputed)
  short* __restrict__ hbf;        // [2,B,H]  bf16 hidden
  short* __restrict__ hmbf;       // [B,H]    bf16 masked bwd hidden
  short* __restrict__ aB;         // [2,B,512] bf16 exp-logits (cols >=500 always 0)
  float* __restrict__ Sp;         // [2,B,32] fp32 softmax partial sums per coltile
  unsigned* __restrict__ bar;     // [2*64] per-dir barrier counters (zeroed per call)
  float* __restrict__ out;        // [B,2H] fp32
};

__device__ __forceinline__ float sigm_(float x) { return 1.f / (1.f + __expf(-x)); }
__device__ __forceinline__ float tanh_(float x) { return 1.f - 2.f / (__expf(2.f * x) + 1.f); }
__device__ __forceinline__ short f2bs(float f) {
  __hip_bfloat16 h = __float2bfloat16(f);
  short s; __builtin_memcpy(&s, &h, 2); return s;
}

// fast per-direction grid barrier: monotonic counter, relaxed spin, thread-0 fences
__device__ __forceinline__ void gsync(unsigned* bar, unsigned target) {
  __syncthreads();                 // all WG mem ops drained (vmcnt0 before s_barrier)
  if (threadIdx.x == 0) {
    __threadfence();               // release: write back XCD L2 to coherence point
    __hip_atomic_fetch_add(bar, 1u, __ATOMIC_RELAXED, __HIP_MEMORY_SCOPE_AGENT);
    while (__hip_atomic_load(bar, __ATOMIC_RELAXED, __HIP_MEMORY_SCOPE_AGENT) < target)
      __builtin_amdgcn_s_sleep(1);
    __threadfence();               // acquire: invalidate stale L1/L2 lines
  }
  __syncthreads();
}

// x fp32 -> bf16, same [B,T,E] layout
__global__ __launch_bounds__(256) void xcvt_kernel(const float* __restrict__ x,
                                                   short* __restrict__ xbf) {
  const size_t i = ((size_t)blockIdx.x * 256 + threadIdx.x) * 8;
  f32x4 a = *reinterpret_cast<const f32x4*>(x + i);
  f32x4 b = *reinterpret_cast<const f32x4*>(x + i + 4);
  sh8 v;
  #pragma unroll
  for (int j = 0; j < 4; ++j) { v[j] = f2bs(a[j]); v[4 + j] = f2bs(b[j]); }
  *reinterpret_cast<sh8*>(xbf + i) = v;
}

// Mfused[d][m][j] = sum_c Mv_d[c][m] * Wih_d[j][E+c]   (fp32)
__global__ __launch_bounds__(256) void mfused_kernel(
    const float* __restrict__ WihF, const float* __restrict__ WihB,
    const float* __restrict__ MvF,  const float* __restrict__ MvB,
    float* __restrict__ Mf) {
  const int d  = blockIdx.x >> 7;
  const int j0 = (blockIdx.x & 127) * 16;
  const float* __restrict__ Wih = d ? WihB : WihF;
  const float* __restrict__ Mv  = d ? MvB  : MvF;
  __shared__ float Wl[16][CTX_ + 1];
  for (int i = threadIdx.x; i < 16 * CTX_; i += 256) {
    int r = i / CTX_, cc = i - r * CTX_;
    Wl[r][cc] = Wih[(size_t)(j0 + r) * EC_ + E_ + cc];
  }
  __syncthreads();
  const int jj = threadIdx.x & 15;
  for (int m = threadIdx.x >> 4; m < MEM_; m += 16) {
    float acc = 0.f;
    for (int cc = 0; cc < CTX_; ++cc)
      acc = fmaf(Mv[cc * MEM_ + m], Wl[jj][cc], acc);
    Mf[(size_t)d * MEM_ * G4_ + (size_t)m * G4_ + j0 + jj] = acc;
  }
}

__global__ __launch_bounds__(256, 1) void scan_kernel(ScanParams p) {
  const int dir  = blockIdx.x >> 7;   // 0 fwd, 1 bwd
  const int w    = blockIdx.x & 127;  // WG within dir: owns cells 4w..4w+3
  const int tid  = threadIdx.x;
  const int wv   = tid >> 6;          // wave 0..3
  const int lane = tid & 63;

  // LDS: weights in MFMA B-fragment order -> linear per-lane ds_read_b128, no conflicts
  __shared__ __align__(16) short WgL[32 * 64 * 8];  // gate W own-cols [16][K=1024] 32 KB
  __shared__ __align__(16) short MkL[16 * 64 * 8];  // attn Mk coltile [16][K=512]  16 KB
  __shared__ __align__(16) short MfL[16 * 64 * 8];  // ctx Mf own-cols [16][K=512]  16 KB
  __shared__ float SvL[B_];                         // 1/softmax-denominator per b
  __shared__ int   LvL[B_];

  const float* __restrict__ Wihd = dir ? p.Wih1 : p.Wih0;
  const float* __restrict__ Whhd = dir ? p.Whh1 : p.Whh0;
  const float* __restrict__ bihd = dir ? p.bih1 : p.bih0;
  const float* __restrict__ bhhd = dir ? p.bhh1 : p.bhh0;
  const float* __restrict__ Mkd  = dir ? p.Mk1  : p.Mk0;
  const float* __restrict__ Mfd  = p.Mf + (size_t)dir * MEM_ * G4_;
  short* __restrict__ hbd  = p.hbf + (size_t)dir * B_ * H_;
  short* __restrict__ aBd  = p.aB  + (size_t)dir * B_ * 512;
  float* __restrict__ Spd  = p.Sp  + (size_t)dir * B_ * 32;
  unsigned* __restrict__ barD = p.bar + dir * 64;   // separate cache lines per dir

  // attn ownership: waves 0,1 of each WG own tile (coltile ct, rowtile mt)
  const int ct = w >> 2;

  // ---- one-time LDS preload (fragment order: [kstep][lane][8]) ----
  for (int i = tid; i < 2048; i += 256) {           // gates: 32 ksteps, OWN cell cols
    const int ks = i >> 6, l2 = i & 63;
    const int col = l2 & 15, kg = l2 >> 4;
    const int k0 = ks * 32 + kg * 8;
    const int gc = (col & 3) * H_ + 4 * w + (col >> 2);  // col c -> gate col of lane c
    const float* src = (k0 < E_) ? (Wihd + (size_t)gc * EC_ + k0)
                                 : (Whhd + (size_t)gc * H_ + (k0 - E_));
    sh8 v;
    #pragma unroll
    for (int j = 0; j < 8; ++j) v[j] = f2bs(src[j]);
    *reinterpret_cast<sh8*>(&WgL[i * 8]) = v;
  }
  for (int i = tid; i < 1024; i += 256) {           // Mk: 16 ksteps
    const int ks = i >> 6, l2 = i & 63;
    const int col = l2 & 15, kg = l2 >> 4;
    const int k0 = ks * 32 + kg * 8;
    const int mr = 16 * ct + col;
    sh8 v;
    #pragma unroll
    for (int j = 0; j < 8; ++j)
      v[j] = (mr < MEM_) ? f2bs(Mkd[(size_t)mr * H_ + k0 + j]) : (short)0;
    *reinterpret_cast<sh8*>(&MkL[i * 8]) = v;
  }
  for (int i = tid; i < 1024; i += 256) {           // Mf cell slice: 16 ksteps
    const int ks = i >> 6, l2 = i & 63;
    const int col = l2 & 15, kg = l2 >> 4;
    const int gc = (col & 3) * H_ + 4 * w + (col >> 2);
    const int k0 = ks * 32 + kg * 8;
    sh8 v;
    #pragma unroll
    for (int j = 0; j < 8; ++j) {
      const int m = k0 + j;
      v[j] = (m < MEM_) ? f2bs(Mfd[(size_t)m * G4_ + gc]) : (short)0;
    }
    *reinterpret_cast<sh8*>(&MfL[i * 8]) = v;
  }
  if (tid < B_) LvL[tid] = p.len[tid];

  // per-lane cell column mapping: c -> (quadrant q, unit offset uu)
  const int c  = lane & 15;
  const int q  = c & 3;
  const int uu = c >> 2;
  const int gcol = q * H_ + 4 * w + uu;
  const float biasl = bihd[gcol] + bhhd[gcol];

  float creg[2][4] = {{0.f,0.f,0.f,0.f},{0.f,0.f,0.f,0.f}};  // cell state in registers
  __syncthreads();

  unsigned bk = 0;   // per-dir barrier epoch

  for (int s = 0; s < T_; ++s) {
    const int t = dir ? (T_ - 1 - s) : s;

    // ===== phase 1a: gate pre-activations for OWN cells (K=1024 MFMA), kept in regs
    f32x4 accG[2] = {(f32x4){0,0,0,0}, (f32x4){0,0,0,0}};
    {
      const int kg8 = (lane >> 4) * 8;
      if (p.xbf) {
        for (int ks = 0; ks < 16; ++ks) {           // x half, bf16 direct
          const int k0 = ks * 32 + kg8;
          sh8 bfrag = *reinterpret_cast<const sh8*>(&WgL[(ks * 64 + lane) * 8]);
          #pragma unroll
          for (int tt = 0; tt < 2; ++tt) {
            const int brow = 32 * wv + 16 * tt + (lane & 15);
            sh8 afrag = *reinterpret_cast<const sh8*>(
                p.xbf + ((size_t)brow * T_ + t) * E_ + k0);
            accG[tt] = __builtin_amdgcn_mfma_f32_16x16x32_bf16(afrag, bfrag, accG[tt], 0, 0, 0);
          }
        }
      } else {
        for (int ks = 0; ks < 16; ++ks) {           // x half, fp32 -> bf16 on the fly
          const int k0 = ks * 32 + kg8;
          sh8 bfrag = *reinterpret_cast<const sh8*>(&WgL[(ks * 64 + lane) * 8]);
          #pragma unroll
          for (int tt = 0; tt < 2; ++tt) {
            const int brow = 32 * wv + 16 * tt + (lane & 15);
            const float* xp = p.x + ((size_t)brow * T_ + t) * E_ + k0;
            f32x4 v0 = *reinterpret_cast<const f32x4*>(xp);
            f32x4 v1 = *reinterpret_cast<const f32x4*>(xp + 4);
            sh8 afrag;
            #pragma unroll
            for (int j = 0; j < 4; ++j) { afrag[j] = f2bs(v0[j]); afrag[4+j] = f2bs(v1[j]); }
            accG[tt] = __builtin_amdgcn_mfma_f32_16x16x32_bf16(afrag, bfrag, accG[tt], 0, 0, 0);
          }
        }
      }
      for (int ks = 16; ks < 32; ++ks) {            // h half (bf16 direct)
        const int kh = (ks - 16) * 32 + kg8;
        sh8 bfrag = *reinterpret_cast<const sh8*>(&WgL[(ks * 64 + lane) * 8]);
        #pragma unroll
        for (int tt = 0; tt < 2; ++tt) {
          const int brow = 32 * wv + 16 * tt + (lane & 15);
          sh8 afrag = *reinterpret_cast<const sh8*>(hbd + brow * H_ + kh);
          accG[tt] = __builtin_amdgcn_mfma_f32_16x16x32_bf16(afrag, bfrag, accG[tt], 0, 0, 0);
        }
      }
    }

    // ===== phase 1b: attn logits -> exp -> aB, partial sums (waves 0,1)
    if (wv < 2) {
      const int uid = 2 * w + wv;
      const int mt  = uid & 7;
      const short* __restrict__ hmem = dir ? p.hmbf : p.hbf;  // bwd reads masked hidden
      const int brow = 16 * mt + (lane & 15);
      const int kg8  = (lane >> 4) * 8;
      f32x4 accA = (f32x4){0,0,0,0};
      for (int ks = 0; ks < 16; ++ks) {
        sh8 afrag = *reinterpret_cast<const sh8*>(hmem + brow * H_ + ks * 32 + kg8);
        sh8 bfrag = *reinterpret_cast<const sh8*>(&MkL[(ks * 64 + lane) * 8]);
        accA = __builtin_amdgcn_mfma_f32_16x16x32_bf16(afrag, bfrag, accA, 0, 0, 0);
      }
      const int m = 16 * ct + (lane & 15);
      float e[4];
      #pragma unroll
      for (int r = 0; r < 4; ++r) e[r] = (m < MEM_) ? __expf(accA[r]) : 0.f;
      #pragma unroll
      for (int r = 0; r < 4; ++r) {
        const int b = 16 * mt + 4 * (lane >> 4) + r;
        aBd[b * 512 + m] = f2bs(e[r]);
      }
      #pragma unroll
      for (int r = 0; r < 4; ++r) {                 // butterfly over the 16 m-lanes
        e[r] += __shfl_xor(e[r], 1);
        e[r] += __shfl_xor(e[r], 2);
        e[r] += __shfl_xor(e[r], 4);
        e[r] += __shfl_xor(e[r], 8);
      }
      if ((lane & 15) == 0) {
        #pragma unroll
        for (int r = 0; r < 4; ++r)
          Spd[(16 * mt + 4 * (lane >> 4) + r) * 32 + ct] = e[r];
      }
    }

    ++bk; gsync(barD, bk * 128u);

    // ===== softmax denominator (deterministic): 1/sum over 32 coltiles
    if (tid < B_) {
      const float* sp = Spd + tid * 32;
      float sm = 0.f;
      #pragma unroll
      for (int i4 = 0; i4 < 8; ++i4) {
        f32x4 v = *reinterpret_cast<const f32x4*>(sp + 4 * i4);
        sm += v[0] + v[1] + v[2] + v[3];
      }
      SvL[tid] = 1.f / sm;
    }

    // ===== phase 2: ctx MFMA for own cell cols (K=512 pad)
    f32x4 accC[2] = {(f32x4){0,0,0,0}, (f32x4){0,0,0,0}};
    if (s > 0) {
      const int kg8 = (lane >> 4) * 8;
      for (int ks = 0; ks < 16; ++ks) {
        sh8 bfrag = *reinterpret_cast<const sh8*>(&MfL[(ks * 64 + lane) * 8]);
        #pragma unroll
        for (int tt = 0; tt < 2; ++tt) {
          const int brow = 32 * wv + 16 * tt + (lane & 15);
          sh8 afrag = *reinterpret_cast<const sh8*>(aBd + brow * 512 + ks * 32 + kg8);
          accC[tt] = __builtin_amdgcn_mfma_f32_16x16x32_bf16(afrag, bfrag, accC[tt], 0, 0, 0);
        }
      }
    }
    __syncthreads();                                // SvL ready for all waves

    // ===== cell update (registers; gate exchange via shfl across q-lanes)
    #pragma unroll
    for (int tt = 0; tt < 2; ++tt) {
      const int b0 = 32 * wv + 16 * tt + 4 * (lane >> 4);
      float g4[4];
      #pragma unroll
      for (int r = 0; r < 4; ++r) {
        float v = accG[tt][r] + biasl;
        if (s > 0) v += accC[tt][r] * SvL[b0 + r];
        g4[r] = v;
      }
      #pragma unroll
      for (int r = 0; r < 4; ++r) {
        const float x1 = __shfl_xor(g4[r], 1);
        const float x2 = __shfl_xor(g4[r], 2);
        const float x3 = __shfl_xor(g4[r], 3);
        const float iv = (q==0)?g4[r]:(q==1)?x1:(q==2)?x2:x3;
        const float fv = (q==0)?x1:(q==1)?g4[r]:(q==2)?x3:x2;
        const float gv = (q==0)?x2:(q==1)?x3:(q==2)?g4[r]:x1;
        const float ov = (q==0)?x3:(q==1)?x2:(q==2)?x1:g4[r];
        float cv = creg[tt][r];
        cv = sigm_(fv) * cv + sigm_(iv) * tanh_(gv);
        const float hv = sigm_(ov) * tanh_(cv);
        creg[tt][r] = cv;
        if (q == 0) {
          const int b    = b0 + r;
          const int unit = 4 * w + uu;
          if (dir == 0) {
            hbd[b * H_ + unit] = f2bs(hv);
            if (t == LvL[b] - 1) p.out[b * (2 * H_) + 2 * unit] = hv;
          } else {
            const short hs = f2bs(hv);
            hbd[b * H_ + unit]    = hs;
            p.hmbf[b * H_ + unit] = (t < LvL[b]) ? hs : (short)0;
            if (s == T_ - 1) p.out[b * (2 * H_) + 2 * unit + 1] = hv;
          }
        }
      }
    }

    ++bk; gsync(barD, bk * 128u);
  }
}

extern "C" void kernel_launch(void* const* d_in, const int* in_sizes, int n_in,
                              void* d_out, int out_size, void* d_ws, size_t ws_size,
                              hipStream_t stream) {
  (void)in_sizes; (void)n_in; (void)out_size;

  ScanParams p;
  p.x    = (const float*)d_in[0];
  p.len  = (const int*)  d_in[1];
  p.Wih0 = (const float*)d_in[2];
  p.Whh0 = (const float*)d_in[3];
  p.bih0 = (const float*)d_in[4];
  p.bhh0 = (const float*)d_in[5];
  p.Wih1 = (const float*)d_in[6];
  p.Whh1 = (const float*)d_in[7];
  p.bih1 = (const float*)d_in[8];
  p.bhh1 = (const float*)d_in[9];
  p.Mk0  = (const float*)d_in[10];
  const float* MvF = (const float*)d_in[11];
  p.Mk1  = (const float*)d_in[12];
  const float* MvB = (const float*)d_in[13];

  char* ws = (char*)d_ws;
  size_t off = 0;
  auto alloc = [&](size_t bytes) -> void* {
    void* ptr = ws + off; off += (bytes + 255) & ~(size_t)255; return ptr;
  };
  float*    Mf   = (float*)   alloc((size_t)2 * MEM_ * G4_ * 4);  // 8.19 MB
  short*    hbf  = (short*)   alloc((size_t)2 * B_ * H_ * 2);     // 256 KB
  short*    hmbf = (short*)   alloc((size_t)B_ * H_ * 2);         // 128 KB
  short*    aB   = (short*)   alloc((size_t)2 * B_ * 512 * 2);    // 256 KB
  float*    Sp   = (float*)   alloc((size_t)2 * B_ * 32 * 4);     // 32 KB
  unsigned* bar  = (unsigned*)alloc(2 * 64 * sizeof(unsigned));   // 512 B
  size_t xbf_off = off;
  short*    xbf  = (short*)   alloc((size_t)B_ * T_ * E_ * 2);    // 67 MB
  const bool useXbf = (ws_size >= xbf_off + (size_t)B_ * T_ * E_ * 2);

  p.Mf = Mf; p.hbf = hbf; p.hmbf = hmbf; p.aB = aB; p.Sp = Sp; p.bar = bar;
  p.xbf = useXbf ? xbf : nullptr;
  p.out = (float*)d_out;

  // zero bf16 recurrent state (hbf,hmbf contiguous) and barrier counters, each call
  hipMemsetAsync(hbf, 0, (size_t)3 * B_ * H_ * 2, stream);
  hipMemsetAsync(bar, 0, 2 * 64 * sizeof(unsigned), stream);

  if (useXbf) {
    const size_t n8 = (size_t)B_ * T_ * E_ / 8;     // 4,194,304 vec8 elems
    xcvt_kernel<<<dim3((unsigned)(n8 / 256)), dim3(256), 0, stream>>>(p.x, xbf);
  }
  mfused_kernel<<<dim3(256), dim3(256), 0, stream>>>(
      (const float*)d_in[2], (const float*)d_in[6], MvF, MvB, Mf);

  void* args[] = { &p };
  hipLaunchCooperativeKernel((const void*)scan_kernel, dim3(256), dim3(256),
                             args, 0, stream);
}

// Round 4
// 20792.430 us; speedup vs baseline: 8.8434x; 1.1459x over previous
//
#include <hip/hip_runtime.h>
#include <hip/hip_bf16.h>

#define T_   512
#define B_   128
#define E_   512
#define H_   512
#define G4_  2048
#define MEM_ 500
#define CTX_ 300
#define EC_  (E_ + CTX_)

typedef short sh8  __attribute__((ext_vector_type(8)));   // 8 bf16 (4 VGPR) MFMA frag
typedef float f32x4 __attribute__((ext_vector_type(4)));

struct ScanParams {
  const float* __restrict__ x;     // [B,T,E] fp32
  const short* __restrict__ xbf;   // [B,T,E] bf16 (ws precomputed; may be null)
  const int*   __restrict__ len;   // [B]
  const float* __restrict__ Wih0; const float* __restrict__ Whh0;
  const float* __restrict__ bih0; const float* __restrict__ bhh0;
  const float* __restrict__ Wih1; const float* __restrict__ Whh1;
  const float* __restrict__ bih1; const float* __restrict__ bhh1;
  const float* __restrict__ Mk0;  const float* __restrict__ Mk1;
  const float* __restrict__ Mf;   // [2,MEM,4H] fp32 (ws, precomputed)
  short* __restrict__ hbf;        // [2par,2dir,B,H]  bf16 hidden
  short* __restrict__ hmbf;       // [2par,B,H]       bf16 masked bwd hidden
  short* __restrict__ aB;         // [2par,2dir,B,512] bf16 exp-logits
  float* __restrict__ Sp;         // [2par,2dir,B,32]  softmax partial sums
  unsigned* __restrict__ bar;     // flag-array barrier state (zeroed per call)
  float* __restrict__ out;        // [B,2H] fp32
};

__device__ __forceinline__ float sigm_(float x) { return 1.f / (1.f + __expf(-x)); }
__device__ __forceinline__ float tanh_(float x) { return 1.f - 2.f / (__expf(2.f * x) + 1.f); }
__device__ __forceinline__ short f2bs(float f) {
  __hip_bfloat16 h = __float2bfloat16(f);
  short s; __builtin_memcpy(&s, &h, 2); return s;
}

// ---- flag-array grid barrier (per direction, 128 WGs, no atomic contention) ----
// slots: 128 x 16 u32 (64B padded). rel: 1 u32. Epochs strictly increase.
__device__ __forceinline__ void bar_arrive(unsigned* slots, int w, unsigned ep) {
  __syncthreads();                 // all waves' stores drained to L2
  if (threadIdx.x == 0) {
    __threadfence();               // release: flush XCD L2 to coherence point
    __hip_atomic_store(&slots[w * 16], ep, __ATOMIC_RELAXED, __HIP_MEMORY_SCOPE_AGENT);
  }
}
__device__ __forceinline__ void bar_wait(unsigned* slots, unsigned* rel, int w, unsigned ep) {
  if (w == 0) {                    // master WG: wave 0 polls all 128 slots
    if (threadIdx.x < 64) {
      const int l = threadIdx.x;
      for (;;) {
        unsigned a = __hip_atomic_load(&slots[l * 16],        __ATOMIC_RELAXED, __HIP_MEMORY_SCOPE_AGENT);
        unsigned b = __hip_atomic_load(&slots[(l + 64) * 16], __ATOMIC_RELAXED, __HIP_MEMORY_SCOPE_AGENT);
        if (__all(a >= ep && b >= ep)) break;
        __builtin_amdgcn_s_sleep(1);
      }
      if (l == 0)
        __hip_atomic_store(rel, ep, __ATOMIC_RELAXED, __HIP_MEMORY_SCOPE_AGENT);
    }
    if (threadIdx.x == 0) __threadfence();   // acquire: invalidate stale L1/L2
    __syncthreads();
  } else {
    if (threadIdx.x == 0) {
      while (__hip_atomic_load(rel, __ATOMIC_RELAXED, __HIP_MEMORY_SCOPE_AGENT) < ep)
        __builtin_amdgcn_s_sleep(1);
      __threadfence();
    }
    __syncthreads();
  }
}

// x fp32 -> bf16, same [B,T,E] layout
__global__ __launch_bounds__(256) void xcvt_kernel(const float* __restrict__ x,
                                                   short* __restrict__ xbf) {
  const size_t i = ((size_t)blockIdx.x * 256 + threadIdx.x) * 8;
  f32x4 a = *reinterpret_cast<const f32x4*>(x + i);
  f32x4 b = *reinterpret_cast<const f32x4*>(x + i + 4);
  sh8 v;
  #pragma unroll
  for (int j = 0; j < 4; ++j) { v[j] = f2bs(a[j]); v[4 + j] = f2bs(b[j]); }
  *reinterpret_cast<sh8*>(xbf + i) = v;
}

// Mfused[d][m][j] = sum_c Mv_d[c][m] * Wih_d[j][E+c]   (fp32)
__global__ __launch_bounds__(256) void mfused_kernel(
    const float* __restrict__ WihF, const float* __restrict__ WihB,
    const float* __restrict__ MvF,  const float* __restrict__ MvB,
    float* __restrict__ Mf) {
  const int d  = blockIdx.x >> 7;
  const int j0 = (blockIdx.x & 127) * 16;
  const float* __restrict__ Wih = d ? WihB : WihF;
  const float* __restrict__ Mv  = d ? MvB  : MvF;
  __shared__ float Wl[16][CTX_ + 1];
  for (int i = threadIdx.x; i < 16 * CTX_; i += 256) {
    int r = i / CTX_, cc = i - r * CTX_;
    Wl[r][cc] = Wih[(size_t)(j0 + r) * EC_ + E_ + cc];
  }
  __syncthreads();
  const int jj = threadIdx.x & 15;
  for (int m = threadIdx.x >> 4; m < MEM_; m += 16) {
    float acc = 0.f;
    for (int cc = 0; cc < CTX_; ++cc)
      acc = fmaf(Mv[cc * MEM_ + m], Wl[jj][cc], acc);
    Mf[(size_t)d * MEM_ * G4_ + (size_t)m * G4_ + j0 + jj] = acc;
  }
}

__global__ __launch_bounds__(256, 1) void scan_kernel(ScanParams p) {
  const int dir  = blockIdx.x >> 7;   // 0 fwd, 1 bwd
  const int w    = blockIdx.x & 127;  // WG within dir: owns cells 4w..4w+3
  const int tid  = threadIdx.x;
  const int wv   = tid >> 6;          // wave 0..3
  const int lane = tid & 63;

  // LDS: weights in MFMA B-fragment order -> linear per-lane ds_read_b128, no conflicts
  __shared__ __align__(16) short WgL[32 * 64 * 8];  // gate W own-cols [16][K=1024] 32 KB
  __shared__ __align__(16) short MkL[16 * 64 * 8];  // attn Mk coltile [16][K=512]  16 KB
  __shared__ __align__(16) short MfL[16 * 64 * 8];  // ctx Mf own-cols [16][K=512]  16 KB
  __shared__ float SvL[B_];                         // 1/softmax-denominator per b
  __shared__ int   LvL[B_];

  const float* __restrict__ Wihd = dir ? p.Wih1 : p.Wih0;
  const float* __restrict__ Whhd = dir ? p.Whh1 : p.Whh0;
  const float* __restrict__ bihd = dir ? p.bih1 : p.bih0;
  const float* __restrict__ bhhd = dir ? p.bhh1 : p.bhh0;
  const float* __restrict__ Mkd  = dir ? p.Mk1  : p.Mk0;
  const float* __restrict__ Mfd  = p.Mf + (size_t)dir * MEM_ * G4_;

  unsigned* __restrict__ slots = p.bar + dir * 2048;          // 128 x 16 u32
  unsigned* __restrict__ rel   = p.bar + 4096 + dir * 64;     // own cache line

  const int ct = w >> 2;   // attn coltile owned by waves 0,1

  // ---- one-time LDS preload (fragment order: [kstep][lane][8]) ----
  for (int i = tid; i < 2048; i += 256) {           // gates: 32 ksteps, OWN cell cols
    const int ks = i >> 6, l2 = i & 63;
    const int col = l2 & 15, kg = l2 >> 4;
    const int k0 = ks * 32 + kg * 8;
    const int gc = (col & 3) * H_ + 4 * w + (col >> 2);
    const float* src = (k0 < E_) ? (Wihd + (size_t)gc * EC_ + k0)
                                 : (Whhd + (size_t)gc * H_ + (k0 - E_));
    sh8 v;
    #pragma unroll
    for (int j = 0; j < 8; ++j) v[j] = f2bs(src[j]);
    *reinterpret_cast<sh8*>(&WgL[i * 8]) = v;
  }
  for (int i = tid; i < 1024; i += 256) {           // Mk: 16 ksteps
    const int ks = i >> 6, l2 = i & 63;
    const int col = l2 & 15, kg = l2 >> 4;
    const int k0 = ks * 32 + kg * 8;
    const int mr = 16 * ct + col;
    sh8 v;
    #pragma unroll
    for (int j = 0; j < 8; ++j)
      v[j] = (mr < MEM_) ? f2bs(Mkd[(size_t)mr * H_ + k0 + j]) : (short)0;
    *reinterpret_cast<sh8*>(&MkL[i * 8]) = v;
  }
  for (int i = tid; i < 1024; i += 256) {           // Mf cell slice: 16 ksteps
    const int ks = i >> 6, l2 = i & 63;
    const int col = l2 & 15, kg = l2 >> 4;
    const int gc = (col & 3) * H_ + 4 * w + (col >> 2);
    const int k0 = ks * 32 + kg * 8;
    sh8 v;
    #pragma unroll
    for (int j = 0; j < 8; ++j) {
      const int m = k0 + j;
      v[j] = (m < MEM_) ? f2bs(Mfd[(size_t)m * G4_ + gc]) : (short)0;
    }
    *reinterpret_cast<sh8*>(&MfL[i * 8]) = v;
  }
  if (tid < B_) LvL[tid] = p.len[tid];

  // per-lane cell column mapping: c -> (quadrant q, unit offset uu)
  const int q  = lane & 3;
  const int uu = (lane & 15) >> 2;
  const int gcol = q * H_ + 4 * w + uu;
  const float biasl = bihd[gcol] + bhhd[gcol];
  const int kg8 = (lane >> 4) * 8;

  float creg[2][4] = {{0.f,0.f,0.f,0.f},{0.f,0.f,0.f,0.f}};  // cell state in registers
  __syncthreads();

  // gate x-half MFMA (no cross-WG dependence) — used to fill barrier-2 windows
  auto xhalf = [&](int t, f32x4* acc) {
    if (p.xbf) {
      for (int ks = 0; ks < 16; ++ks) {
        sh8 bfrag = *reinterpret_cast<const sh8*>(&WgL[(ks * 64 + lane) * 8]);
        #pragma unroll
        for (int tt = 0; tt < 2; ++tt) {
          const int brow = 32 * wv + 16 * tt + (lane & 15);
          sh8 afrag = *reinterpret_cast<const sh8*>(
              p.xbf + ((size_t)brow * T_ + t) * E_ + ks * 32 + kg8);
          acc[tt] = __builtin_amdgcn_mfma_f32_16x16x32_bf16(afrag, bfrag, acc[tt], 0, 0, 0);
        }
      }
    } else {
      for (int ks = 0; ks < 16; ++ks) {
        sh8 bfrag = *reinterpret_cast<const sh8*>(&WgL[(ks * 64 + lane) * 8]);
        #pragma unroll
        for (int tt = 0; tt < 2; ++tt) {
          const int brow = 32 * wv + 16 * tt + (lane & 15);
          const float* xp = p.x + ((size_t)brow * T_ + t) * E_ + ks * 32 + kg8;
          f32x4 v0 = *reinterpret_cast<const f32x4*>(xp);
          f32x4 v1 = *reinterpret_cast<const f32x4*>(xp + 4);
          sh8 afrag;
          #pragma unroll
          for (int j = 0; j < 4; ++j) { afrag[j] = f2bs(v0[j]); afrag[4+j] = f2bs(v1[j]); }
          acc[tt] = __builtin_amdgcn_mfma_f32_16x16x32_bf16(afrag, bfrag, acc[tt], 0, 0, 0);
        }
      }
    }
  };

  f32x4 accG[2] = {(f32x4){0,0,0,0}, (f32x4){0,0,0,0}};
  xhalf(dir ? T_ - 1 : 0, accG);                    // prologue: x-half for step 0

  for (int s = 0; s < T_; ++s) {
    const int t   = dir ? (T_ - 1 - s) : s;
    const int cur = s & 1, prv = cur ^ 1;
    const short* __restrict__ hb_prev = p.hbf + ((size_t)(prv * 2 + dir)) * B_ * H_;
    short*       __restrict__ hb_cur  = p.hbf + ((size_t)(cur * 2 + dir)) * B_ * H_;
    const short* __restrict__ hm_prev = p.hmbf + (size_t)prv * B_ * H_;
    short*       __restrict__ hm_cur  = p.hmbf + (size_t)cur * B_ * H_;
    short*       __restrict__ aB_cur  = p.aB + ((size_t)(cur * 2 + dir)) * B_ * 512;
    float*       __restrict__ Sp_cur  = p.Sp + ((size_t)(cur * 2 + dir)) * B_ * 32;

    // ===== phase 1b FIRST: attn logits -> exp -> aB[cur], partial sums (waves 0,1)
    if (wv < 2) {
      const int mt   = (2 * w + wv) & 7;
      const short* __restrict__ hmem = dir ? hm_prev : hb_prev;
      const int brow = 16 * mt + (lane & 15);
      f32x4 accA = (f32x4){0,0,0,0};
      for (int ks = 0; ks < 16; ++ks) {
        sh8 afrag = *reinterpret_cast<const sh8*>(hmem + brow * H_ + ks * 32 + kg8);
        sh8 bfrag = *reinterpret_cast<const sh8*>(&MkL[(ks * 64 + lane) * 8]);
        accA = __builtin_amdgcn_mfma_f32_16x16x32_bf16(afrag, bfrag, accA, 0, 0, 0);
      }
      const int m = 16 * ct + (lane & 15);
      float e[4];
      #pragma unroll
      for (int r = 0; r < 4; ++r) e[r] = (m < MEM_) ? __expf(accA[r]) : 0.f;
      #pragma unroll
      for (int r = 0; r < 4; ++r)
        aB_cur[(16 * mt + 4 * (lane >> 4) + r) * 512 + m] = f2bs(e[r]);
      #pragma unroll
      for (int r = 0; r < 4; ++r) {                 // butterfly over the 16 m-lanes
        e[r] += __shfl_xor(e[r], 1);
        e[r] += __shfl_xor(e[r], 2);
        e[r] += __shfl_xor(e[r], 4);
        e[r] += __shfl_xor(e[r], 8);
      }
      if ((lane & 15) == 0) {
        #pragma unroll
        for (int r = 0; r < 4; ++r)
          Sp_cur[(16 * mt + 4 * (lane >> 4) + r) * 32 + ct] = e[r];
      }
    }

    const unsigned ep1 = 2 * s + 1, ep2 = 2 * s + 2;
    bar_arrive(slots, w, ep1);

    // ===== overlap: gate h-half MFMA (reads stable h[prev]) while others arrive
    for (int ks = 0; ks < 16; ++ks) {
      sh8 bfrag = *reinterpret_cast<const sh8*>(&WgL[((16 + ks) * 64 + lane) * 8]);
      #pragma unroll
      for (int tt = 0; tt < 2; ++tt) {
        const int brow = 32 * wv + 16 * tt + (lane & 15);
        sh8 afrag = *reinterpret_cast<const sh8*>(hb_prev + brow * H_ + ks * 32 + kg8);
        accG[tt] = __builtin_amdgcn_mfma_f32_16x16x32_bf16(afrag, bfrag, accG[tt], 0, 0, 0);
      }
    }

    bar_wait(slots, rel, w, ep1);

    // ===== softmax denominator (deterministic): 1/sum over 32 coltiles
    if (tid < B_) {
      const float* sp = Sp_cur + tid * 32;
      float sm = 0.f;
      #pragma unroll
      for (int i4 = 0; i4 < 8; ++i4) {
        f32x4 v = *reinterpret_cast<const f32x4*>(sp + 4 * i4);
        sm += v[0] + v[1] + v[2] + v[3];
      }
      SvL[tid] = 1.f / sm;
    }

    // ===== phase 2: ctx MFMA for own cell cols (K=512 pad)
    f32x4 accC[2] = {(f32x4){0,0,0,0}, (f32x4){0,0,0,0}};
    if (s > 0) {
      for (int ks = 0; ks < 16; ++ks) {
        sh8 bfrag = *reinterpret_cast<const sh8*>(&MfL[(ks * 64 + lane) * 8]);
        #pragma unroll
        for (int tt = 0; tt < 2; ++tt) {
          const int brow = 32 * wv + 16 * tt + (lane & 15);
          sh8 afrag = *reinterpret_cast<const sh8*>(aB_cur + brow * 512 + ks * 32 + kg8);
          accC[tt] = __builtin_amdgcn_mfma_f32_16x16x32_bf16(afrag, bfrag, accC[tt], 0, 0, 0);
        }
      }
    }
    __syncthreads();                                // SvL ready for all waves

    // ===== cell update (registers; gate exchange via shfl across q-lanes)
    #pragma unroll
    for (int tt = 0; tt < 2; ++tt) {
      const int b0 = 32 * wv + 16 * tt + 4 * (lane >> 4);
      float g4[4];
      #pragma unroll
      for (int r = 0; r < 4; ++r) {
        float v = accG[tt][r] + biasl;
        if (s > 0) v += accC[tt][r] * SvL[b0 + r];
        g4[r] = v;
      }
      #pragma unroll
      for (int r = 0; r < 4; ++r) {
        const float x1 = __shfl_xor(g4[r], 1);
        const float x2 = __shfl_xor(g4[r], 2);
        const float x3 = __shfl_xor(g4[r], 3);
        const float iv = (q==0)?g4[r]:(q==1)?x1:(q==2)?x2:x3;
        const float fv = (q==0)?x1:(q==1)?g4[r]:(q==2)?x3:x2;
        const float gv = (q==0)?x2:(q==1)?x3:(q==2)?g4[r]:x1;
        const float ov = (q==0)?x3:(q==1)?x2:(q==2)?x1:g4[r];
        float cv = creg[tt][r];
        cv = sigm_(fv) * cv + sigm_(iv) * tanh_(gv);
        const float hv = sigm_(ov) * tanh_(cv);
        creg[tt][r] = cv;
        if (q == 0) {
          const int b    = b0 + r;
          const int unit = 4 * w + uu;
          if (dir == 0) {
            hb_cur[b * H_ + unit] = f2bs(hv);
            if (t == LvL[b] - 1) p.out[b * (2 * H_) + 2 * unit] = hv;
          } else {
            const short hs = f2bs(hv);
            hb_cur[b * H_ + unit] = hs;
            hm_cur[b * H_ + unit] = (t < LvL[b]) ? hs : (short)0;
            if (s == T_ - 1) p.out[b * (2 * H_) + 2 * unit + 1] = hv;
          }
        }
      }
    }

    bar_arrive(slots, w, ep2);

    // ===== overlap: next step's gate x-half (xbf only, no cross-WG dependence)
    accG[0] = (f32x4){0,0,0,0}; accG[1] = (f32x4){0,0,0,0};
    if (s + 1 < T_) xhalf(dir ? (T_ - 2 - s) : (s + 1), accG);

    bar_wait(slots, rel, w, ep2);
  }
}

extern "C" void kernel_launch(void* const* d_in, const int* in_sizes, int n_in,
                              void* d_out, int out_size, void* d_ws, size_t ws_size,
                              hipStream_t stream) {
  (void)in_sizes; (void)n_in; (void)out_size;

  ScanParams p;
  p.x    = (const float*)d_in[0];
  p.len  = (const int*)  d_in[1];
  p.Wih0 = (const float*)d_in[2];
  p.Whh0 = (const float*)d_in[3];
  p.bih0 = (const float*)d_in[4];
  p.bhh0 = (const float*)d_in[5];
  p.Wih1 = (const float*)d_in[6];
  p.Whh1 = (const float*)d_in[7];
  p.bih1 = (const float*)d_in[8];
  p.bhh1 = (const float*)d_in[9];
  p.Mk0  = (const float*)d_in[10];
  const float* MvF = (const float*)d_in[11];
  p.Mk1  = (const float*)d_in[12];
  const float* MvB = (const float*)d_in[13];

  char* ws = (char*)d_ws;
  size_t off = 0;
  auto alloc = [&](size_t bytes) -> void* {
    void* ptr = ws + off; off += (bytes + 255) & ~(size_t)255; return ptr;
  };
  float*    Mf   = (float*)   alloc((size_t)2 * MEM_ * G4_ * 4);      // 8.19 MB
  short*    hbf  = (short*)   alloc((size_t)2 * 2 * B_ * H_ * 2);     // 512 KB (2 par)
  short*    hmbf = (short*)   alloc((size_t)2 * B_ * H_ * 2);         // 256 KB (2 par)
  short*    aB   = (short*)   alloc((size_t)2 * 2 * B_ * 512 * 2);    // 512 KB (2 par)
  float*    Sp   = (float*)   alloc((size_t)2 * 2 * B_ * 32 * 4);     // 64 KB (2 par)
  unsigned* bar  = (unsigned*)alloc((4096 + 2 * 64) * sizeof(unsigned)); // 16.9 KB
  size_t xbf_off = off;
  short*    xbf  = (short*)   alloc((size_t)B_ * T_ * E_ * 2);        // 67 MB
  const bool useXbf = (ws_size >= xbf_off + (size_t)B_ * T_ * E_ * 2);

  p.Mf = Mf; p.hbf = hbf; p.hmbf = hmbf; p.aB = aB; p.Sp = Sp; p.bar = bar;
  p.xbf = useXbf ? xbf : nullptr;
  p.out = (float*)d_out;

  // zero bf16 recurrent state (hbf,hmbf contiguous) and barrier state, each call
  hipMemsetAsync(hbf, 0, (size_t)(2 * 2 + 2) * B_ * H_ * 2, stream);
  hipMemsetAsync(bar, 0, (4096 + 2 * 64) * sizeof(unsigned), stream);

  if (useXbf) {
    const size_t n8 = (size_t)B_ * T_ * E_ / 8;
    xcvt_kernel<<<dim3((unsigned)(n8 / 256)), dim3(256), 0, stream>>>(p.x, xbf);
  }
  mfused_kernel<<<dim3(256), dim3(256), 0, stream>>>(
      (const float*)d_in[2], (const float*)d_in[6], MvF, MvB, Mf);

  void* args[] = { &p };
  hipLaunchCooperativeKernel((const void*)scan_kernel, dim3(256), dim3(256),
                             args, 0, stream);
}

// Round 6
// 10474.174 us; speedup vs baseline: 17.5551x; 1.9851x over previous
//
#include <hip/hip_runtime.h>
#include <hip/hip_bf16.h>

#define T_   512
#define B_   128
#define E_   512
#define H_   512
#define G4_  2048
#define MEM_ 500
#define CTX_ 300
#define EC_  (E_ + CTX_)

typedef short sh8  __attribute__((ext_vector_type(8)));   // 8 bf16 (4 VGPR) MFMA frag
typedef float f32x4 __attribute__((ext_vector_type(4)));

struct ScanParams {
  const float* __restrict__ x;     // [B,T,E] fp32
  const short* __restrict__ xbf;   // [B,T,E] bf16 (ws precomputed; may be null)
  const int*   __restrict__ len;   // [B]
  const float* __restrict__ Wih0; const float* __restrict__ Whh0;
  const float* __restrict__ bih0; const float* __restrict__ bhh0;
  const float* __restrict__ Wih1; const float* __restrict__ Whh1;
  const float* __restrict__ bih1; const float* __restrict__ bhh1;
  const float* __restrict__ Mk0;  const float* __restrict__ Mk1;
  const float* __restrict__ Mf;   // [2,MEM,4H] fp32 (ws, precomputed)
  short* __restrict__ hbf;        // [2par,2dir,B,H]  bf16 hidden
  short* __restrict__ hmbf;       // [2par,B,H]       bf16 masked bwd hidden
  short* __restrict__ aB;         // [2dir,B,512] bf16 exp-logits (single buffer)
  unsigned* __restrict__ bar;     // flag-array barrier state (zeroed per call)
  float* __restrict__ out;        // [B,2H] fp32
};

__device__ __forceinline__ float sigm_(float x) { return 1.f / (1.f + __expf(-x)); }
__device__ __forceinline__ float tanh_(float x) { return 1.f - 2.f / (__expf(2.f * x) + 1.f); }
__device__ __forceinline__ short f2bs(float f) {
  __hip_bfloat16 h = __float2bfloat16(f);
  short s; __builtin_memcpy(&s, &h, 2); return s;
}
__device__ __forceinline__ float bs2f(short s) {
  unsigned u = ((unsigned)(unsigned short)s) << 16;
  float f; __builtin_memcpy(&f, &u, 4); return f;
}

// ---- batched L2-bypass loads: 16x dwordx4 from one base, stride 64B, one wait ----
struct F16 { sh8 v[16]; };
__device__ __forceinline__ void gld16(F16& f, const short* base) {
  asm volatile(
      "global_load_dwordx4 %0, %16, off sc0 sc1\n\t"
      "global_load_dwordx4 %1, %16, off offset:64 sc0 sc1\n\t"
      "global_load_dwordx4 %2, %16, off offset:128 sc0 sc1\n\t"
      "global_load_dwordx4 %3, %16, off offset:192 sc0 sc1\n\t"
      "global_load_dwordx4 %4, %16, off offset:256 sc0 sc1\n\t"
      "global_load_dwordx4 %5, %16, off offset:320 sc0 sc1\n\t"
      "global_load_dwordx4 %6, %16, off offset:384 sc0 sc1\n\t"
      "global_load_dwordx4 %7, %16, off offset:448 sc0 sc1\n\t"
      "global_load_dwordx4 %8, %16, off offset:512 sc0 sc1\n\t"
      "global_load_dwordx4 %9, %16, off offset:576 sc0 sc1\n\t"
      "global_load_dwordx4 %10, %16, off offset:640 sc0 sc1\n\t"
      "global_load_dwordx4 %11, %16, off offset:704 sc0 sc1\n\t"
      "global_load_dwordx4 %12, %16, off offset:768 sc0 sc1\n\t"
      "global_load_dwordx4 %13, %16, off offset:832 sc0 sc1\n\t"
      "global_load_dwordx4 %14, %16, off offset:896 sc0 sc1\n\t"
      "global_load_dwordx4 %15, %16, off offset:960 sc0 sc1\n\t"
      "s_waitcnt vmcnt(0)"
      : "=&v"(f.v[0]), "=&v"(f.v[1]), "=&v"(f.v[2]), "=&v"(f.v[3]),
        "=&v"(f.v[4]), "=&v"(f.v[5]), "=&v"(f.v[6]), "=&v"(f.v[7]),
        "=&v"(f.v[8]), "=&v"(f.v[9]), "=&v"(f.v[10]), "=&v"(f.v[11]),
        "=&v"(f.v[12]), "=&v"(f.v[13]), "=&v"(f.v[14]), "=&v"(f.v[15])
      : "v"(base)
      : "memory");
}

// 4 short stores (b-stride 1024B) + drain
__device__ __forceinline__ void st4s(short* base, unsigned d0, unsigned d1,
                                     unsigned d2, unsigned d3) {
  asm volatile(
      "global_store_short %4, %0, off sc0 sc1\n\t"
      "global_store_short %4, %1, off offset:1024 sc0 sc1\n\t"
      "global_store_short %4, %2, off offset:2048 sc0 sc1\n\t"
      "global_store_short %4, %3, off offset:3072 sc0 sc1\n\t"
      "s_waitcnt vmcnt(0)"
      :: "v"(d0), "v"(d1), "v"(d2), "v"(d3), "v"(base) : "memory");
}

// 8 short stores: rows +0..3 (1024B apart) at +0 and +8 bytes (no wait; caller drains)
__device__ __forceinline__ void st8s(short* base, const unsigned* d) {
  asm volatile(
      "global_store_short %8, %0, off sc0 sc1\n\t"
      "global_store_short %8, %1, off offset:1024 sc0 sc1\n\t"
      "global_store_short %8, %2, off offset:2048 sc0 sc1\n\t"
      "global_store_short %8, %3, off offset:3072 sc0 sc1\n\t"
      "global_store_short %8, %4, off offset:8 sc0 sc1\n\t"
      "global_store_short %8, %5, off offset:1032 sc0 sc1\n\t"
      "global_store_short %8, %6, off offset:2056 sc0 sc1\n\t"
      "global_store_short %8, %7, off offset:3080 sc0 sc1"
      :: "v"(d[0]), "v"(d[1]), "v"(d[2]), "v"(d[3]),
         "v"(d[4]), "v"(d[5]), "v"(d[6]), "v"(d[7]), "v"(base) : "memory");
}

// ---- flag-array grid barrier (64 WGs/dir), NO cache maintenance (all sc1) ----
__device__ __forceinline__ void bar_arrive(unsigned* slots, int w, unsigned ep) {
  __syncthreads();                 // all waves reached; asm stores already drained
  if (threadIdx.x == 0)
    __hip_atomic_store(&slots[w * 16], ep, __ATOMIC_RELAXED, __HIP_MEMORY_SCOPE_AGENT);
}
__device__ __forceinline__ void bar_wait(unsigned* slots, unsigned* rel, int w, unsigned ep) {
  if (w == 0) {                    // master WG: wave 0 polls all 64 slots (1 load/lane)
    if (threadIdx.x < 64) {
      const int l = threadIdx.x;
      for (;;) {
        unsigned a = __hip_atomic_load(&slots[l * 16], __ATOMIC_RELAXED, __HIP_MEMORY_SCOPE_AGENT);
        if (__all(a >= ep)) break;
        __builtin_amdgcn_s_sleep(1);
      }
      if (l == 0)
        __hip_atomic_store(rel, ep, __ATOMIC_RELAXED, __HIP_MEMORY_SCOPE_AGENT);
    }
    __syncthreads();
  } else {
    if (threadIdx.x == 0) {
      while (__hip_atomic_load(rel, __ATOMIC_RELAXED, __HIP_MEMORY_SCOPE_AGENT) < ep)
        __builtin_amdgcn_s_sleep(1);
    }
    __syncthreads();
  }
}

// x fp32 -> bf16, same [B,T,E] layout
__global__ __launch_bounds__(256) void xcvt_kernel(const float* __restrict__ x,
                                                   short* __restrict__ xbf) {
  const size_t i = ((size_t)blockIdx.x * 256 + threadIdx.x) * 8;
  f32x4 a = *reinterpret_cast<const f32x4*>(x + i);
  f32x4 b = *reinterpret_cast<const f32x4*>(x + i + 4);
  sh8 v;
  #pragma unroll
  for (int j = 0; j < 4; ++j) { v[j] = f2bs(a[j]); v[4 + j] = f2bs(b[j]); }
  *reinterpret_cast<sh8*>(xbf + i) = v;
}

// Mfused[d][m][j] = sum_c Mv_d[c][m] * Wih_d[j][E+c]   (fp32)
__global__ __launch_bounds__(256) void mfused_kernel(
    const float* __restrict__ WihF, const float* __restrict__ WihB,
    const float* __restrict__ MvF,  const float* __restrict__ MvB,
    float* __restrict__ Mf) {
  const int d  = blockIdx.x >> 7;
  const int j0 = (blockIdx.x & 127) * 16;
  const float* __restrict__ Wih = d ? WihB : WihF;
  const float* __restrict__ Mv  = d ? MvB  : MvF;
  __shared__ float Wl[16][CTX_ + 1];
  for (int i = threadIdx.x; i < 16 * CTX_; i += 256) {
    int r = i / CTX_, cc = i - r * CTX_;
    Wl[r][cc] = Wih[(size_t)(j0 + r) * EC_ + E_ + cc];
  }
  __syncthreads();
  const int jj = threadIdx.x & 15;
  for (int m = threadIdx.x >> 4; m < MEM_; m += 16) {
    float acc = 0.f;
    for (int cc = 0; cc < CTX_; ++cc)
      acc = fmaf(Mv[cc * MEM_ + m], Wl[jj][cc], acc);
    Mf[(size_t)d * MEM_ * G4_ + (size_t)m * G4_ + j0 + jj] = acc;
  }
}

__global__ __launch_bounds__(512, 1) void scan_kernel(ScanParams p) {
  const int dir  = blockIdx.x >> 6;   // 0 fwd, 1 bwd (64 WGs each)
  const int w    = blockIdx.x & 63;   // WG within dir: owns cells 8w..8w+7
  const int tid  = threadIdx.x;
  const int wv   = tid >> 6;          // wave 0..7
  const int lane = tid & 63;

  // weights in MFMA B-fragment order -> linear per-lane ds_read_b128, no conflicts
  __shared__ __align__(16) short WgL[32 * 2 * 64 * 8];  // [ks][ct2][lane][8] 64 KB
  __shared__ __align__(16) short MkL[16 * 64 * 8];      // 16 KB
  __shared__ __align__(16) short MfL[16 * 2 * 64 * 8];  // 32 KB
  __shared__ int LvL[B_];

  const float* __restrict__ Wihd = dir ? p.Wih1 : p.Wih0;
  const float* __restrict__ Whhd = dir ? p.Whh1 : p.Whh0;
  const float* __restrict__ bihd = dir ? p.bih1 : p.bih0;
  const float* __restrict__ bhhd = dir ? p.bhh1 : p.bhh0;
  const float* __restrict__ Mkd  = dir ? p.Mk1  : p.Mk0;
  const float* __restrict__ Mfd  = p.Mf + (size_t)dir * MEM_ * G4_;
  short* __restrict__ aBd = p.aB + (size_t)dir * B_ * 512;

  unsigned* __restrict__ slots = p.bar + dir * 2048;          // 64 x 16 u32 used
  unsigned* __restrict__ rel   = p.bar + 4096 + dir * 64;     // own cache line

  const int ct = w >> 1;   // attn m-coltile (0..31); row-tiles (w&1)*4 + wv, wv<4

  // ---- one-time LDS preload (fragment order) ----
  for (int i = tid; i < 32 * 2 * 64; i += 512) {    // gates: [ks][ct2][lane]
    const int ks = i >> 7, r2 = i & 127, ct2 = r2 >> 6, l2 = r2 & 63;
    const int col = l2 & 15, kg = l2 >> 4;
    const int k0 = ks * 32 + kg * 8;
    const int gc = (col & 3) * H_ + 8 * w + 4 * ct2 + (col >> 2);
    const float* src = (k0 < E_) ? (Wihd + (size_t)gc * EC_ + k0)
                                 : (Whhd + (size_t)gc * H_ + (k0 - E_));
    sh8 v;
    #pragma unroll
    for (int j = 0; j < 8; ++j) v[j] = f2bs(src[j]);
    *reinterpret_cast<sh8*>(&WgL[i * 8]) = v;
  }
  for (int i = tid; i < 16 * 64; i += 512) {        // Mk: [ks][lane]
    const int ks = i >> 6, l2 = i & 63;
    const int col = l2 & 15, kg = l2 >> 4;
    const int k0 = ks * 32 + kg * 8;
    const int mr = 16 * ct + col;
    sh8 v;
    #pragma unroll
    for (int j = 0; j < 8; ++j)
      v[j] = (mr < MEM_) ? f2bs(Mkd[(size_t)mr * H_ + k0 + j]) : (short)0;
    *reinterpret_cast<sh8*>(&MkL[i * 8]) = v;
  }
  for (int i = tid; i < 16 * 2 * 64; i += 512) {    // Mf: [ks][ct2][lane]
    const int ks = i >> 7, r2 = i & 127, ct2 = r2 >> 6, l2 = r2 & 63;
    const int col = l2 & 15, kg = l2 >> 4;
    const int gc = (col & 3) * H_ + 8 * w + 4 * ct2 + (col >> 2);
    const int m0 = ks * 32 + kg * 8;
    sh8 v;
    #pragma unroll
    for (int j = 0; j < 8; ++j)
      v[j] = (m0 + j < MEM_) ? f2bs(Mfd[(size_t)(m0 + j) * G4_ + gc]) : (short)0;
    *reinterpret_cast<sh8*>(&MfL[i * 8]) = v;
  }
  if (tid < B_) LvL[tid] = p.len[tid];

  // per-lane cell mapping: col cc=lane&15 -> quadrant q, unit offset uu; 2 coltiles
  const int cc  = lane & 15;
  const int q   = cc & 3;
  const int uu  = cc >> 2;
  const int kg8 = (lane >> 4) * 8;
  const int arow = lane & 15;
  float biasl[2];
  #pragma unroll
  for (int ct2 = 0; ct2 < 2; ++ct2) {
    const int gc = q * H_ + 8 * w + 4 * ct2 + uu;
    biasl[ct2] = bihd[gc] + bhhd[gc];
  }

  float creg[2][4] = {{0.f,0.f,0.f,0.f},{0.f,0.f,0.f,0.f}};
  __syncthreads();

  // gate x-half MFMA (xbf only, no cross-WG dependence) — fills barrier-2 windows
  auto xhalf = [&](int t, f32x4* acc) {
    if (p.xbf) {
      const short* xb = p.xbf + ((size_t)(16 * wv + arow) * T_ + t) * E_ + kg8;
      for (int ks = 0; ks < 16; ++ks) {
        sh8 af = *reinterpret_cast<const sh8*>(xb + ks * 32);
        acc[0] = __builtin_amdgcn_mfma_f32_16x16x32_bf16(
            af, *reinterpret_cast<const sh8*>(&WgL[((ks * 2 + 0) * 64 + lane) * 8]), acc[0], 0, 0, 0);
        acc[1] = __builtin_amdgcn_mfma_f32_16x16x32_bf16(
            af, *reinterpret_cast<const sh8*>(&WgL[((ks * 2 + 1) * 64 + lane) * 8]), acc[1], 0, 0, 0);
      }
    } else {
      const float* xp0 = p.x + ((size_t)(16 * wv + arow) * T_ + t) * E_ + kg8;
      for (int ks = 0; ks < 16; ++ks) {
        f32x4 v0 = *reinterpret_cast<const f32x4*>(xp0 + ks * 32);
        f32x4 v1 = *reinterpret_cast<const f32x4*>(xp0 + ks * 32 + 4);
        sh8 af;
        #pragma unroll
        for (int j = 0; j < 4; ++j) { af[j] = f2bs(v0[j]); af[4 + j] = f2bs(v1[j]); }
        acc[0] = __builtin_amdgcn_mfma_f32_16x16x32_bf16(
            af, *reinterpret_cast<const sh8*>(&WgL[((ks * 2 + 0) * 64 + lane) * 8]), acc[0], 0, 0, 0);
        acc[1] = __builtin_amdgcn_mfma_f32_16x16x32_bf16(
            af, *reinterpret_cast<const sh8*>(&WgL[((ks * 2 + 1) * 64 + lane) * 8]), acc[1], 0, 0, 0);
      }
    }
  };

  f32x4 accG[2] = {(f32x4){0,0,0,0}, (f32x4){0,0,0,0}};
  xhalf(dir ? T_ - 1 : 0, accG);                    // prologue: x-half for step 0

  for (int s = 0; s < T_; ++s) {
    const int t   = dir ? (T_ - 1 - s) : s;
    const int cur = s & 1, prv = cur ^ 1;
    const short* __restrict__ hb_prev = p.hbf + ((size_t)(prv * 2 + dir)) * B_ * H_;
    short*       __restrict__ hb_cur  = p.hbf + ((size_t)(cur * 2 + dir)) * B_ * H_;
    const short* __restrict__ hm_prev = p.hmbf + (size_t)prv * B_ * H_;
    short*       __restrict__ hm_cur  = p.hmbf + (size_t)cur * B_ * H_;

    // ===== phase 1b: attn logits -> exp -> aB (waves 0-3; sc1 end-to-end)
    if (wv < 4) {
      const int mt = (w & 1) * 4 + wv;              // row-tile 0..7
      const short* __restrict__ hmem = dir ? hm_prev : hb_prev;
      F16 fA;
      gld16(fA, hmem + (size_t)(16 * mt + arow) * H_ + kg8);
      f32x4 accA = (f32x4){0, 0, 0, 0};
      for (int ks = 0; ks < 16; ++ks)
        accA = __builtin_amdgcn_mfma_f32_16x16x32_bf16(
            fA.v[ks], *reinterpret_cast<const sh8*>(&MkL[(ks * 64 + lane) * 8]), accA, 0, 0, 0);
      const int m = 16 * ct + arow;
      unsigned d[4];
      #pragma unroll
      for (int r = 0; r < 4; ++r) {
        float e = (m < MEM_) ? __expf(accA[r]) : 0.f;
        d[r] = (unsigned)(unsigned short)f2bs(e);
      }
      st4s(aBd + (size_t)(16 * mt + 4 * (lane >> 4)) * 512 + m, d[0], d[1], d[2], d[3]);
    }

    const unsigned ep1 = 2 * s + 1, ep2 = 2 * s + 2;
    bar_arrive(slots, w, ep1);

    // ===== overlap: gate h-half MFMA (reads stable h[prev], sc1) while others arrive
    {
      F16 fH;
      gld16(fH, hb_prev + (size_t)(16 * wv + arow) * H_ + kg8);
      for (int ks = 0; ks < 16; ++ks) {
        accG[0] = __builtin_amdgcn_mfma_f32_16x16x32_bf16(
            fH.v[ks], *reinterpret_cast<const sh8*>(&WgL[(((16 + ks) * 2 + 0) * 64 + lane) * 8]), accG[0], 0, 0, 0);
        accG[1] = __builtin_amdgcn_mfma_f32_16x16x32_bf16(
            fH.v[ks], *reinterpret_cast<const sh8*>(&WgL[(((16 + ks) * 2 + 1) * 64 + lane) * 8]), accG[1], 0, 0, 0);
      }
    }

    bar_wait(slots, rel, w, ep1);

    // ===== phase 2: ctx MFMA + local softmax denominator (from same fragments)
    f32x4 accC[2] = {(f32x4){0,0,0,0}, (f32x4){0,0,0,0}};
    float rs = 0.f;
    if (s > 0) {
      F16 fC;
      gld16(fC, aBd + (size_t)(16 * wv + arow) * 512 + kg8);
      for (int ks = 0; ks < 16; ++ks) {
        accC[0] = __builtin_amdgcn_mfma_f32_16x16x32_bf16(
            fC.v[ks], *reinterpret_cast<const sh8*>(&MfL[((ks * 2 + 0) * 64 + lane) * 8]), accC[0], 0, 0, 0);
        accC[1] = __builtin_amdgcn_mfma_f32_16x16x32_bf16(
            fC.v[ks], *reinterpret_cast<const sh8*>(&MfL[((ks * 2 + 1) * 64 + lane) * 8]), accC[1], 0, 0, 0);
        #pragma unroll
        for (int j = 0; j < 8; ++j) rs += bs2f(fC.v[ks][j]);
      }
      rs += __shfl_xor(rs, 16);
      rs += __shfl_xor(rs, 32);                     // lane holds rowsum of row 16*wv+arow
    }
    float inv4[4];
    #pragma unroll
    for (int r = 0; r < 4; ++r)
      inv4[r] = (s > 0) ? 1.f / __shfl(rs, 4 * (lane >> 4) + r) : 0.f;

    // ===== cell update (registers; gate exchange via shfl across q-lanes)
    unsigned hsd[8]; unsigned hmd[8]; float hvv[2][4];
    #pragma unroll
    for (int ct2 = 0; ct2 < 2; ++ct2) {
      float g4[4];
      #pragma unroll
      for (int r = 0; r < 4; ++r) {
        float v = accG[ct2][r] + biasl[ct2];
        if (s > 0) v += accC[ct2][r] * inv4[r];
        g4[r] = v;
      }
      #pragma unroll
      for (int r = 0; r < 4; ++r) {
        const float x1 = __shfl_xor(g4[r], 1);
        const float x2 = __shfl_xor(g4[r], 2);
        const float x3 = __shfl_xor(g4[r], 3);
        const float iv = (q==0)?g4[r]:(q==1)?x1:(q==2)?x2:x3;
        const float fv = (q==0)?x1:(q==1)?g4[r]:(q==2)?x3:x2;
        const float gv = (q==0)?x2:(q==1)?x3:(q==2)?g4[r]:x1;
        const float ov = (q==0)?x3:(q==1)?x2:(q==2)?x1:g4[r];
        float cv = creg[ct2][r];
        cv = sigm_(fv) * cv + sigm_(iv) * tanh_(gv);
        const float hv = sigm_(ov) * tanh_(cv);
        creg[ct2][r] = cv;
        hvv[ct2][r] = hv;
        const short hs = f2bs(hv);
        hsd[ct2 * 4 + r] = (unsigned)(unsigned short)hs;
        if (dir) {
          const int b = 16 * wv + 4 * (lane >> 4) + r;
          hmd[ct2 * 4 + r] = (t < LvL[b]) ? hsd[ct2 * 4 + r] : 0u;
        }
      }
    }
    if (q == 0) {
      const int b0 = 16 * wv + 4 * (lane >> 4);
      const int unit0 = 8 * w + uu;                 // <=511 now (w<=63)
      unsigned hord[8] = {hsd[0],hsd[1],hsd[2],hsd[3],hsd[4],hsd[5],hsd[6],hsd[7]};
      st8s(hb_cur + (size_t)b0 * H_ + unit0, hord);
      if (dir) {
        unsigned mord[8] = {hmd[0],hmd[1],hmd[2],hmd[3],hmd[4],hmd[5],hmd[6],hmd[7]};
        st8s(hm_cur + (size_t)b0 * H_ + unit0, mord);
      }
      #pragma unroll
      for (int ct2 = 0; ct2 < 2; ++ct2) {
        #pragma unroll
        for (int r = 0; r < 4; ++r) {
          const int b = b0 + r;
          const int unit = unit0 + 4 * ct2;
          if (dir == 0) {
            if (t == LvL[b] - 1) p.out[b * (2 * H_) + 2 * unit] = hvv[ct2][r];
          } else {
            if (s == T_ - 1) p.out[b * (2 * H_) + 2 * unit + 1] = hvv[ct2][r];
          }
        }
      }
    }
    asm volatile("s_waitcnt vmcnt(0)" ::: "memory");   // drain sc1 h/hm stores

    bar_arrive(slots, w, ep2);

    // ===== overlap: next step's gate x-half (local data only)
    accG[0] = (f32x4){0,0,0,0}; accG[1] = (f32x4){0,0,0,0};
    if (s + 1 < T_) xhalf(dir ? (T_ - 2 - s) : (s + 1), accG);

    bar_wait(slots, rel, w, ep2);
  }
}

extern "C" void kernel_launch(void* const* d_in, const int* in_sizes, int n_in,
                              void* d_out, int out_size, void* d_ws, size_t ws_size,
                              hipStream_t stream) {
  (void)in_sizes; (void)n_in; (void)out_size;

  ScanParams p;
  p.x    = (const float*)d_in[0];
  p.len  = (const int*)  d_in[1];
  p.Wih0 = (const float*)d_in[2];
  p.Whh0 = (const float*)d_in[3];
  p.bih0 = (const float*)d_in[4];
  p.bhh0 = (const float*)d_in[5];
  p.Wih1 = (const float*)d_in[6];
  p.Whh1 = (const float*)d_in[7];
  p.bih1 = (const float*)d_in[8];
  p.bhh1 = (const float*)d_in[9];
  p.Mk0  = (const float*)d_in[10];
  const float* MvF = (const float*)d_in[11];
  p.Mk1  = (const float*)d_in[12];
  const float* MvB = (const float*)d_in[13];

  char* ws = (char*)d_ws;
  size_t off = 0;
  auto alloc = [&](size_t bytes) -> void* {
    void* ptr = ws + off; off += (bytes + 255) & ~(size_t)255; return ptr;
  };
  float*    Mf   = (float*)   alloc((size_t)2 * MEM_ * G4_ * 4);      // 8.19 MB
  short*    hbf  = (short*)   alloc((size_t)2 * 2 * B_ * H_ * 2);     // 512 KB (2 par)
  short*    hmbf = (short*)   alloc((size_t)2 * B_ * H_ * 2);         // 256 KB (2 par)
  short*    aB   = (short*)   alloc((size_t)2 * B_ * 512 * 2);        // 256 KB
  unsigned* bar  = (unsigned*)alloc((4096 + 2 * 64) * sizeof(unsigned));
  size_t xbf_off = off;
  short*    xbf  = (short*)   alloc((size_t)B_ * T_ * E_ * 2);        // 67 MB
  const bool useXbf = (ws_size >= xbf_off + (size_t)B_ * T_ * E_ * 2);

  p.Mf = Mf; p.hbf = hbf; p.hmbf = hmbf; p.aB = aB; p.bar = bar;
  p.xbf = useXbf ? xbf : nullptr;
  p.out = (float*)d_out;

  // zero bf16 recurrent state (hbf,hmbf contiguous) and barrier state, each call
  hipMemsetAsync(hbf, 0, (size_t)(2 * 2 + 2) * B_ * H_ * 2, stream);
  hipMemsetAsync(bar, 0, (4096 + 2 * 64) * sizeof(unsigned), stream);

  if (useXbf) {
    const size_t n8 = (size_t)B_ * T_ * E_ / 8;
    xcvt_kernel<<<dim3((unsigned)(n8 / 256)), dim3(256), 0, stream>>>(p.x, xbf);
  }
  mfused_kernel<<<dim3(256), dim3(256), 0, stream>>>(
      (const float*)d_in[2], (const float*)d_in[6], MvF, MvB, Mf);

  void* args[] = { &p };
  hipLaunchCooperativeKernel((const void*)scan_kernel, dim3(128), dim3(512),
                             args, 0, stream);
}

// Round 10
// 9677.128 us; speedup vs baseline: 19.0010x; 1.0824x over previous
//
#include <hip/hip_runtime.h>
#include <hip/hip_bf16.h>

#define T_   512
#define B_   128
#define E_   512
#define H_   512
#define G4_  2048
#define MEM_ 500
#define CTX_ 300
#define EC_  (E_ + CTX_)
#define SPIN_MAX 65536

typedef short sh8  __attribute__((ext_vector_type(8)));   // 8 bf16 (4 VGPR) MFMA frag
typedef float f32x4 __attribute__((ext_vector_type(4)));

struct ScanParams {
  const float* __restrict__ x;     // [B,T,E] fp32
  const short* __restrict__ xbf;   // [B,T,E] bf16 (ws precomputed; may be null)
  const int*   __restrict__ len;   // [B]
  const float* __restrict__ Wih0; const float* __restrict__ Whh0;
  const float* __restrict__ bih0; const float* __restrict__ bhh0;
  const float* __restrict__ Wih1; const float* __restrict__ Whh1;
  const float* __restrict__ bih1; const float* __restrict__ bhh1;
  const float* __restrict__ Mk0;  const float* __restrict__ Mk1;
  const float* __restrict__ Mf;   // [2,MEM,4H] fp32 (ws, precomputed)
  short* __restrict__ hbf;        // [2par,2dir,B,H]  bf16 hidden
  short* __restrict__ hmbf;       // [2par,B,H]       bf16 masked bwd hidden
  short* __restrict__ aB;         // [2dir,B,512] bf16 exp-logits (single buffer)
  unsigned* __restrict__ bar;     // per-wave flag arrays (zeroed per call)
  float* __restrict__ out;        // [B,2H] fp32
};

__device__ __forceinline__ float sigm_(float x) { return 1.f / (1.f + __expf(-x)); }
__device__ __forceinline__ float tanh_(float x) { return 1.f - 2.f / (__expf(2.f * x) + 1.f); }
__device__ __forceinline__ short f2bs(float f) {
  __hip_bfloat16 h = __float2bfloat16(f);
  short s; __builtin_memcpy(&s, &h, 2); return s;
}
__device__ __forceinline__ float bs2f(short s) {
  unsigned u = ((unsigned)(unsigned short)s) << 16;
  float f; __builtin_memcpy(&f, &u, 4); return f;
}

// ---- batched L2-bypass loads: 16x dwordx4 from one base, stride 64B ----
// CONTRACT: waits vmcnt(0) INSIDE the asm — outputs valid at block exit, and no
// phantom outstanding VMEM ops can skew the compiler's own waitcnt bookkeeping.
struct F16 { sh8 v[16]; };
__device__ __forceinline__ void gld16(F16& f, const short* base) {
  asm volatile(
      "global_load_dwordx4 %0, %16, off sc0 sc1\n\t"
      "global_load_dwordx4 %1, %16, off offset:64 sc0 sc1\n\t"
      "global_load_dwordx4 %2, %16, off offset:128 sc0 sc1\n\t"
      "global_load_dwordx4 %3, %16, off offset:192 sc0 sc1\n\t"
      "global_load_dwordx4 %4, %16, off offset:256 sc0 sc1\n\t"
      "global_load_dwordx4 %5, %16, off offset:320 sc0 sc1\n\t"
      "global_load_dwordx4 %6, %16, off offset:384 sc0 sc1\n\t"
      "global_load_dwordx4 %7, %16, off offset:448 sc0 sc1\n\t"
      "global_load_dwordx4 %8, %16, off offset:512 sc0 sc1\n\t"
      "global_load_dwordx4 %9, %16, off offset:576 sc0 sc1\n\t"
      "global_load_dwordx4 %10, %16, off offset:640 sc0 sc1\n\t"
      "global_load_dwordx4 %11, %16, off offset:704 sc0 sc1\n\t"
      "global_load_dwordx4 %12, %16, off offset:768 sc0 sc1\n\t"
      "global_load_dwordx4 %13, %16, off offset:832 sc0 sc1\n\t"
      "global_load_dwordx4 %14, %16, off offset:896 sc0 sc1\n\t"
      "global_load_dwordx4 %15, %16, off offset:960 sc0 sc1\n\t"
      "s_waitcnt vmcnt(0)"
      : "=&v"(f.v[0]), "=&v"(f.v[1]), "=&v"(f.v[2]), "=&v"(f.v[3]),
        "=&v"(f.v[4]), "=&v"(f.v[5]), "=&v"(f.v[6]), "=&v"(f.v[7]),
        "=&v"(f.v[8]), "=&v"(f.v[9]), "=&v"(f.v[10]), "=&v"(f.v[11]),
        "=&v"(f.v[12]), "=&v"(f.v[13]), "=&v"(f.v[14]), "=&v"(f.v[15])
      : "v"(base)
      : "memory");
}

// 4 short stores (b-stride 1024B) + internal drain
__device__ __forceinline__ void st4s(short* base, unsigned d0, unsigned d1,
                                     unsigned d2, unsigned d3) {
  asm volatile(
      "global_store_short %4, %0, off sc0 sc1\n\t"
      "global_store_short %4, %1, off offset:1024 sc0 sc1\n\t"
      "global_store_short %4, %2, off offset:2048 sc0 sc1\n\t"
      "global_store_short %4, %3, off offset:3072 sc0 sc1\n\t"
      "s_waitcnt vmcnt(0)"
      :: "v"(d0), "v"(d1), "v"(d2), "v"(d3), "v"(base) : "memory");
}

// 8 short stores: rows +0..3 (1024B apart) at +0 and +8 bytes (no wait; caller
// drains immediately after the out-store block, exactly as the passing r6 did)
__device__ __forceinline__ void st8s(short* base, const unsigned* d) {
  asm volatile(
      "global_store_short %8, %0, off sc0 sc1\n\t"
      "global_store_short %8, %1, off offset:1024 sc0 sc1\n\t"
      "global_store_short %8, %2, off offset:2048 sc0 sc1\n\t"
      "global_store_short %8, %3, off offset:3072 sc0 sc1\n\t"
      "global_store_short %8, %4, off offset:8 sc0 sc1\n\t"
      "global_store_short %8, %5, off offset:1032 sc0 sc1\n\t"
      "global_store_short %8, %6, off offset:2056 sc0 sc1\n\t"
      "global_store_short %8, %7, off offset:3080 sc0 sc1"
      :: "v"(d[0]), "v"(d[1]), "v"(d[2]), "v"(d[3]),
         "v"(d[4]), "v"(d[5]), "v"(d[6]), "v"(d[7]), "v"(base) : "memory");
}

// ---- per-wave flag helpers (epoch-monotonic, agent scope, no fences) ----
__device__ __forceinline__ bool hchk(const unsigned* hfl, int wv, unsigned ep, int lane) {
  unsigned v = __hip_atomic_load(&hfl[((lane * 8) + wv) * 16],
                                 __ATOMIC_RELAXED, __HIP_MEMORY_SCOPE_AGENT);
  return __all((int)(v >= ep));
}
__device__ __forceinline__ bool achk(const unsigned* afl, int wv, unsigned ep, int lane) {
  unsigned v = __hip_atomic_load(&afl[(((lane & 31) * 8) + wv) * 16],
                                 __ATOMIC_RELAXED, __HIP_MEMORY_SCOPE_AGENT);
  return __all((int)(v >= ep));
}
__device__ __forceinline__ void spin_h(const unsigned* hfl, int wv, unsigned ep, int lane) {
  int n = 0;
  while (!hchk(hfl, wv, ep, lane) && n < SPIN_MAX) { __builtin_amdgcn_s_sleep(1); ++n; }
}
__device__ __forceinline__ void spin_a(const unsigned* afl, int wv, unsigned ep, int lane) {
  int n = 0;
  while (!achk(afl, wv, ep, lane) && n < SPIN_MAX) { __builtin_amdgcn_s_sleep(1); ++n; }
}
__device__ __forceinline__ void fset(unsigned* slot, unsigned ep, int lane) {
  if (lane == 0)
    __hip_atomic_store(slot, ep, __ATOMIC_RELAXED, __HIP_MEMORY_SCOPE_AGENT);
}

// x fp32 -> bf16, same [B,T,E] layout
__global__ __launch_bounds__(256) void xcvt_kernel(const float* __restrict__ x,
                                                   short* __restrict__ xbf) {
  const size_t i = ((size_t)blockIdx.x * 256 + threadIdx.x) * 8;
  f32x4 a = *reinterpret_cast<const f32x4*>(x + i);
  f32x4 b = *reinterpret_cast<const f32x4*>(x + i + 4);
  sh8 v;
  #pragma unroll
  for (int j = 0; j < 4; ++j) { v[j] = f2bs(a[j]); v[4 + j] = f2bs(b[j]); }
  *reinterpret_cast<sh8*>(xbf + i) = v;
}

// Mfused[d][m][j] = sum_c Mv_d[c][m] * Wih_d[j][E+c]   (fp32)
__global__ __launch_bounds__(256) void mfused_kernel(
    const float* __restrict__ WihF, const float* __restrict__ WihB,
    const float* __restrict__ MvF,  const float* __restrict__ MvB,
    float* __restrict__ Mf) {
  const int d  = blockIdx.x >> 7;
  const int j0 = (blockIdx.x & 127) * 16;
  const float* __restrict__ Wih = d ? WihB : WihF;
  const float* __restrict__ Mv  = d ? MvB  : MvF;
  __shared__ float Wl[16][CTX_ + 1];
  for (int i = threadIdx.x; i < 16 * CTX_; i += 256) {
    int r = i / CTX_, cc = i - r * CTX_;
    Wl[r][cc] = Wih[(size_t)(j0 + r) * EC_ + E_ + cc];
  }
  __syncthreads();
  const int jj = threadIdx.x & 15;
  for (int m = threadIdx.x >> 4; m < MEM_; m += 16) {
    float acc = 0.f;
    for (int cc = 0; cc < CTX_; ++cc)
      acc = fmaf(Mv[cc * MEM_ + m], Wl[jj][cc], acc);
    Mf[(size_t)d * MEM_ * G4_ + (size_t)m * G4_ + j0 + jj] = acc;
  }
}

__global__ __launch_bounds__(512, 1) void scan_kernel(ScanParams p) {
  const int dir  = blockIdx.x >> 6;   // 0 fwd, 1 bwd (64 WGs each)
  const int w    = blockIdx.x & 63;   // WG within dir: owns cells 8w..8w+7
  const int tid  = threadIdx.x;
  const int wv   = tid >> 6;          // wave 0..7 == batch row-tile owner
  const int lane = tid & 63;

  // weights in MFMA B-fragment order -> linear per-lane ds_read_b128, no conflicts
  __shared__ __align__(16) short WgL[32 * 2 * 64 * 8];  // [ks][ct2][lane][8] 64 KB
  __shared__ __align__(16) short MkL[16 * 64 * 8];      // 16 KB
  __shared__ __align__(16) short MfL[16 * 2 * 64 * 8];  // 32 KB
  __shared__ int LvL[B_];

  const float* __restrict__ Wihd = dir ? p.Wih1 : p.Wih0;
  const float* __restrict__ Whhd = dir ? p.Whh1 : p.Whh0;
  const float* __restrict__ bihd = dir ? p.bih1 : p.bih0;
  const float* __restrict__ bhhd = dir ? p.bhh1 : p.bhh0;
  const float* __restrict__ Mkd  = dir ? p.Mk1  : p.Mk0;
  const float* __restrict__ Mfd  = p.Mf + (size_t)dir * MEM_ * G4_;
  short* __restrict__ aBd = p.aB + (size_t)dir * B_ * 512;

  // flag arrays: hfl[dir][w][wv], afl[dir][ct][wv]; 64B-strided slots
  unsigned* __restrict__ hflD = p.bar + (size_t)dir * 64 * 8 * 16;
  unsigned* __restrict__ aflD = p.bar + 16384 + (size_t)dir * 32 * 8 * 16;

  const bool prod = ((w & 1) == dir);   // attention producer WGs
  const int  ct   = w >> 1;             // attn m-coltile 0..31 (producers)

  // ---- one-time LDS preload (fragment order) ----
  for (int i = tid; i < 32 * 2 * 64; i += 512) {    // gates: [ks][ct2][lane]
    const int ks = i >> 7, r2 = i & 127, ct2 = r2 >> 6, l2 = r2 & 63;
    const int col = l2 & 15, kg = l2 >> 4;
    const int k0 = ks * 32 + kg * 8;
    const int gc = (col & 3) * H_ + 8 * w + 4 * ct2 + (col >> 2);
    const float* src = (k0 < E_) ? (Wihd + (size_t)gc * EC_ + k0)
                                 : (Whhd + (size_t)gc * H_ + (k0 - E_));
    sh8 v;
    #pragma unroll
    for (int j = 0; j < 8; ++j) v[j] = f2bs(src[j]);
    *reinterpret_cast<sh8*>(&WgL[i * 8]) = v;
  }
  for (int i = tid; i < 16 * 64; i += 512) {        // Mk: [ks][lane]
    const int ks = i >> 6, l2 = i & 63;
    const int col = l2 & 15, kg = l2 >> 4;
    const int k0 = ks * 32 + kg * 8;
    const int mr = 16 * ct + col;
    sh8 v;
    #pragma unroll
    for (int j = 0; j < 8; ++j)
      v[j] = (mr < MEM_) ? f2bs(Mkd[(size_t)mr * H_ + k0 + j]) : (short)0;
    *reinterpret_cast<sh8*>(&MkL[i * 8]) = v;
  }
  for (int i = tid; i < 16 * 2 * 64; i += 512) {    // Mf: [ks][ct2][lane]
    const int ks = i >> 7, r2 = i & 127, ct2 = r2 >> 6, l2 = r2 & 63;
    const int col = l2 & 15, kg = l2 >> 4;
    const int gc = (col & 3) * H_ + 8 * w + 4 * ct2 + (col >> 2);
    const int m0 = ks * 32 + kg * 8;
    sh8 v;
    #pragma unroll
    for (int j = 0; j < 8; ++j)
      v[j] = (m0 + j < MEM_) ? f2bs(Mfd[(size_t)(m0 + j) * G4_ + gc]) : (short)0;
    *reinterpret_cast<sh8*>(&MfL[i * 8]) = v;
  }
  if (tid < B_) LvL[tid] = p.len[tid];

  // per-lane cell mapping
  const int cc  = lane & 15;
  const int q   = cc & 3;
  const int uu  = cc >> 2;
  const int kg8 = (lane >> 4) * 8;
  const int arow = lane & 15;
  float biasl[2];
  #pragma unroll
  for (int ct2 = 0; ct2 < 2; ++ct2) {
    const int gc = q * H_ + 8 * w + 4 * ct2 + uu;
    biasl[ct2] = bihd[gc] + bhhd[gc];
  }

  float creg[2][4] = {{0.f,0.f,0.f,0.f},{0.f,0.f,0.f,0.f}};
  __syncthreads();                     // LDS + LvL ready (only barrier in kernel)

  // gate x-half MFMA (xbf / x only; no cross-WG dependence)
  auto xhalf = [&](int t, f32x4* acc) {
    if (p.xbf) {
      const short* xb = p.xbf + ((size_t)(16 * wv + arow) * T_ + t) * E_ + kg8;
      for (int ks = 0; ks < 16; ++ks) {
        sh8 af = *reinterpret_cast<const sh8*>(xb + ks * 32);
        acc[0] = __builtin_amdgcn_mfma_f32_16x16x32_bf16(
            af, *reinterpret_cast<const sh8*>(&WgL[((ks * 2 + 0) * 64 + lane) * 8]), acc[0], 0, 0, 0);
        acc[1] = __builtin_amdgcn_mfma_f32_16x16x32_bf16(
            af, *reinterpret_cast<const sh8*>(&WgL[((ks * 2 + 1) * 64 + lane) * 8]), acc[1], 0, 0, 0);
      }
    } else {
      const float* xp0 = p.x + ((size_t)(16 * wv + arow) * T_ + t) * E_ + kg8;
      for (int ks = 0; ks < 16; ++ks) {
        f32x4 v0 = *reinterpret_cast<const f32x4*>(xp0 + ks * 32);
        f32x4 v1 = *reinterpret_cast<const f32x4*>(xp0 + ks * 32 + 4);
        sh8 af;
        #pragma unroll
        for (int j = 0; j < 4; ++j) { af[j] = f2bs(v0[j]); af[4 + j] = f2bs(v1[j]); }
        acc[0] = __builtin_amdgcn_mfma_f32_16x16x32_bf16(
            af, *reinterpret_cast<const sh8*>(&WgL[((ks * 2 + 0) * 64 + lane) * 8]), acc[0], 0, 0, 0);
        acc[1] = __builtin_amdgcn_mfma_f32_16x16x32_bf16(
            af, *reinterpret_cast<const sh8*>(&WgL[((ks * 2 + 1) * 64 + lane) * 8]), acc[1], 0, 0, 0);
      }
    }
  };

  f32x4 accG[2] = {(f32x4){0,0,0,0}, (f32x4){0,0,0,0}};
  xhalf(dir ? T_ - 1 : 0, accG);                    // prologue: x-half for step 0

  const bool bwdprod = prod && dir;

  for (int s = 0; s < T_; ++s) {
    const int t   = dir ? (T_ - 1 - s) : s;
    const int cur = s & 1, prv = cur ^ 1;
    const short* __restrict__ hb_prev = p.hbf + ((size_t)(prv * 2 + dir)) * B_ * H_;
    short*       __restrict__ hb_cur  = p.hbf + ((size_t)(cur * 2 + dir)) * B_ * H_;
    const short* __restrict__ hm_prev = p.hmbf + (size_t)prv * B_ * H_;
    short*       __restrict__ hm_cur  = p.hmbf + (size_t)cur * B_ * H_;

    const short* hrow = hb_prev + (size_t)(16 * wv + arow) * H_ + kg8;
    const short* mrow = hm_prev + (size_t)(16 * wv + arow) * H_ + kg8;

    // ===== A: wait h-flags of step s-1 FIRST, then issue waited loads
    if (s > 0) spin_h(hflD, wv, (unsigned)s, lane);
    __builtin_amdgcn_sched_barrier(0);
    F16 fH, fM;
    gld16(fH, hrow);
    if (bwdprod) gld16(fM, mrow);

    // ===== B: producers: attn logits -> exp -> aB + flag (rows = own wv tile)
    if (prod) {
      f32x4 accA = (f32x4){0, 0, 0, 0};
      if (dir) {
        for (int ks = 0; ks < 16; ++ks)
          accA = __builtin_amdgcn_mfma_f32_16x16x32_bf16(
              fM.v[ks], *reinterpret_cast<const sh8*>(&MkL[(ks * 64 + lane) * 8]), accA, 0, 0, 0);
      } else {
        for (int ks = 0; ks < 16; ++ks)
          accA = __builtin_amdgcn_mfma_f32_16x16x32_bf16(
              fH.v[ks], *reinterpret_cast<const sh8*>(&MkL[(ks * 64 + lane) * 8]), accA, 0, 0, 0);
      }
      const int m = 16 * ct + arow;
      unsigned d[4];
      #pragma unroll
      for (int r = 0; r < 4; ++r) {
        float e = (m < MEM_) ? __expf(accA[r]) : 0.f;
        d[r] = (unsigned)(unsigned short)f2bs(e);
      }
      st4s(aBd + (size_t)(16 * wv + 4 * (lane >> 4)) * 512 + m, d[0], d[1], d[2], d[3]);
      fset(&aflD[(ct * 8 + wv) * 16], (unsigned)(s + 1), lane);
    }

    // ===== C: gate h-half MFMA (fH only) — overlaps other waves' attn/store time
    for (int ks = 0; ks < 16; ++ks) {
      accG[0] = __builtin_amdgcn_mfma_f32_16x16x32_bf16(
          fH.v[ks], *reinterpret_cast<const sh8*>(&WgL[(((16 + ks) * 2 + 0) * 64 + lane) * 8]), accG[0], 0, 0, 0);
      accG[1] = __builtin_amdgcn_mfma_f32_16x16x32_bf16(
          fH.v[ks], *reinterpret_cast<const sh8*>(&WgL[(((16 + ks) * 2 + 1) * 64 + lane) * 8]), accG[1], 0, 0, 0);
    }

    // ===== D: wait aB flags, waited fC load, ctx MFMA + local softmax denom
    f32x4 accC[2] = {(f32x4){0,0,0,0}, (f32x4){0,0,0,0}};
    float inv4[4] = {0.f, 0.f, 0.f, 0.f};
    if (s > 0) {
      spin_a(aflD, wv, (unsigned)(s + 1), lane);
      __builtin_amdgcn_sched_barrier(0);
      F16 fC;
      gld16(fC, aBd + (size_t)(16 * wv + arow) * 512 + kg8);
      float rs = 0.f;
      for (int ks = 0; ks < 16; ++ks) {
        accC[0] = __builtin_amdgcn_mfma_f32_16x16x32_bf16(
            fC.v[ks], *reinterpret_cast<const sh8*>(&MfL[((ks * 2 + 0) * 64 + lane) * 8]), accC[0], 0, 0, 0);
        accC[1] = __builtin_amdgcn_mfma_f32_16x16x32_bf16(
            fC.v[ks], *reinterpret_cast<const sh8*>(&MfL[((ks * 2 + 1) * 64 + lane) * 8]), accC[1], 0, 0, 0);
        #pragma unroll
        for (int j = 0; j < 8; ++j) rs += bs2f(fC.v[ks][j]);
      }
      rs += __shfl_xor(rs, 16);
      rs += __shfl_xor(rs, 32);                     // lane holds rowsum(16wv+arow)
      #pragma unroll
      for (int r = 0; r < 4; ++r)
        inv4[r] = 1.f / __shfl(rs, 4 * (lane >> 4) + r);
    }

    // ===== E: cell update + h/hm stores + h-flag
    unsigned hsd[8]; unsigned hmd[8]; float hvv[2][4];
    #pragma unroll
    for (int ct2 = 0; ct2 < 2; ++ct2) {
      float g4[4];
      #pragma unroll
      for (int r = 0; r < 4; ++r) {
        float v = accG[ct2][r] + biasl[ct2];
        if (s > 0) v += accC[ct2][r] * inv4[r];
        g4[r] = v;
      }
      #pragma unroll
      for (int r = 0; r < 4; ++r) {
        const float x1 = __shfl_xor(g4[r], 1);
        const float x2 = __shfl_xor(g4[r], 2);
        const float x3 = __shfl_xor(g4[r], 3);
        const float iv = (q==0)?g4[r]:(q==1)?x1:(q==2)?x2:x3;
        const float fv = (q==0)?x1:(q==1)?g4[r]:(q==2)?x3:x2;
        const float gv = (q==0)?x2:(q==1)?x3:(q==2)?g4[r]:x1;
        const float ov = (q==0)?x3:(q==1)?x2:(q==2)?x1:g4[r];
        float cv = creg[ct2][r];
        cv = sigm_(fv) * cv + sigm_(iv) * tanh_(gv);
        const float hv = sigm_(ov) * tanh_(cv);
        creg[ct2][r] = cv;
        hvv[ct2][r] = hv;
        const short hs = f2bs(hv);
        hsd[ct2 * 4 + r] = (unsigned)(unsigned short)hs;
        if (dir) {
          const int b = 16 * wv + 4 * (lane >> 4) + r;
          hmd[ct2 * 4 + r] = (t < LvL[b]) ? hsd[ct2 * 4 + r] : 0u;
        }
      }
    }
    if (q == 0) {
      const int b0 = 16 * wv + 4 * (lane >> 4);
      const int unit0 = 8 * w + uu;
      unsigned hord[8] = {hsd[0],hsd[1],hsd[2],hsd[3],hsd[4],hsd[5],hsd[6],hsd[7]};
      st8s(hb_cur + (size_t)b0 * H_ + unit0, hord);
      if (dir) {
        unsigned mord[8] = {hmd[0],hmd[1],hmd[2],hmd[3],hmd[4],hmd[5],hmd[6],hmd[7]};
        st8s(hm_cur + (size_t)b0 * H_ + unit0, mord);
      }
      #pragma unroll
      for (int ct2 = 0; ct2 < 2; ++ct2) {
        #pragma unroll
        for (int r = 0; r < 4; ++r) {
          const int b = b0 + r;
          const int unit = unit0 + 4 * ct2;
          if (dir == 0) {
            if (t == LvL[b] - 1) p.out[b * (2 * H_) + 2 * unit] = hvv[ct2][r];
          } else {
            if (s == T_ - 1) p.out[b * (2 * H_) + 2 * unit + 1] = hvv[ct2][r];
          }
        }
      }
    }
    asm volatile("s_waitcnt vmcnt(0)" ::: "memory");   // drain sc1 h/hm stores
    fset(&hflD[(w * 8 + wv) * 16], (unsigned)(s + 1), lane);

    // ===== F: next step's gate x-half prefetch (local data only)
    accG[0] = (f32x4){0,0,0,0}; accG[1] = (f32x4){0,0,0,0};
    if (s + 1 < T_) xhalf(dir ? (T_ - 2 - s) : (s + 1), accG);
  }
}

extern "C" void kernel_launch(void* const* d_in, const int* in_sizes, int n_in,
                              void* d_out, int out_size, void* d_ws, size_t ws_size,
                              hipStream_t stream) {
  (void)in_sizes; (void)n_in; (void)out_size;

  ScanParams p;
  p.x    = (const float*)d_in[0];
  p.len  = (const int*)  d_in[1];
  p.Wih0 = (const float*)d_in[2];
  p.Whh0 = (const float*)d_in[3];
  p.bih0 = (const float*)d_in[4];
  p.bhh0 = (const float*)d_in[5];
  p.Wih1 = (const float*)d_in[6];
  p.Whh1 = (const float*)d_in[7];
  p.bih1 = (const float*)d_in[8];
  p.bhh1 = (const float*)d_in[9];
  p.Mk0  = (const float*)d_in[10];
  const float* MvF = (const float*)d_in[11];
  p.Mk1  = (const float*)d_in[12];
  const float* MvB = (const float*)d_in[13];

  char* ws = (char*)d_ws;
  size_t off = 0;
  auto alloc = [&](size_t bytes) -> void* {
    void* ptr = ws + off; off += (bytes + 255) & ~(size_t)255; return ptr;
  };
  float*    Mf   = (float*)   alloc((size_t)2 * MEM_ * G4_ * 4);      // 8.19 MB
  short*    hbf  = (short*)   alloc((size_t)2 * 2 * B_ * H_ * 2);     // 512 KB (2 par)
  short*    hmbf = (short*)   alloc((size_t)2 * B_ * H_ * 2);         // 256 KB (2 par)
  short*    aB   = (short*)   alloc((size_t)2 * B_ * 512 * 2);        // 256 KB
  unsigned* bar  = (unsigned*)alloc((size_t)24576 * sizeof(unsigned));// 96 KB flags
  size_t xbf_off = off;
  short*    xbf  = (short*)   alloc((size_t)B_ * T_ * E_ * 2);        // 67 MB
  const bool useXbf = (ws_size >= xbf_off + (size_t)B_ * T_ * E_ * 2);

  p.Mf = Mf; p.hbf = hbf; p.hmbf = hmbf; p.aB = aB; p.bar = bar;
  p.xbf = useXbf ? xbf : nullptr;
  p.out = (float*)d_out;

  // zero bf16 recurrent state (hbf,hmbf contiguous) and flag state, each call
  hipMemsetAsync(hbf, 0, (size_t)(2 * 2 + 2) * B_ * H_ * 2, stream);
  hipMemsetAsync(bar, 0, (size_t)24576 * sizeof(unsigned), stream);

  if (useXbf) {
    const size_t n8 = (size_t)B_ * T_ * E_ / 8;
    xcvt_kernel<<<dim3((unsigned)(n8 / 256)), dim3(256), 0, stream>>>(p.x, xbf);
  }
  mfused_kernel<<<dim3(256), dim3(256), 0, stream>>>(
      (const float*)d_in[2], (const float*)d_in[6], MvF, MvB, Mf);

  void* args[] = { &p };
  hipLaunchCooperativeKernel((const void*)scan_kernel, dim3(128), dim3(512),
                             args, 0, stream);
}